// Round 2
// baseline (1065.451 us; speedup 1.0000x reference)
//
#include <hip/hip_runtime.h>
#include <hip/hip_bf16.h>

// MHA forward, fp32 I/O, MI355X (gfx950).
// All matmuls via bf16 split-precision MFMA (x = hi + lo bf16;
// x*y ~= hi*hi + hi*lo + lo*hi, fp32 accum) -> ~fp32 accuracy at up to
// 833 TF useful (2.5 PF / 3). No fp32-input MFMA exists on CDNA4.
//
// Pipeline: 3 projection GEMMs -> flash attention -> output GEMM.
// Workspace (96 MB): Qp, Kp, Vp fp32 [B*S,1024] head-interleaved; attention
// output Ctx ALIASES Qp (safe: each block reads its Q rows before the first
// barrier and writes the same rows/cols after the last barrier).

typedef __attribute__((ext_vector_type(8))) short bf16x8;
typedef __attribute__((ext_vector_type(4))) float f32x4;
typedef __attribute__((ext_vector_type(4))) float fvec4;
typedef __attribute__((ext_vector_type(4))) unsigned int uvec4;
typedef __attribute__((ext_vector_type(4))) unsigned short usvec4;

#define MFMA16(a, b, c) __builtin_amdgcn_mfma_f32_16x16x32_bf16((a), (b), (c), 0, 0, 0)

static __device__ __forceinline__ unsigned short f2bf(float f) {
  unsigned u = __builtin_bit_cast(unsigned, f);
  unsigned r = u + 0x7FFFu + ((u >> 16) & 1u);  // RNE
  return (unsigned short)(r >> 16);
}
static __device__ __forceinline__ float bf2f(unsigned short h) {
  unsigned u = ((unsigned)h) << 16;
  return __builtin_bit_cast(float, u);
}
static __device__ __forceinline__ void split2(float x, unsigned short& hi, unsigned short& lo) {
  hi = f2bf(x);
  lo = f2bf(x - bf2f(hi));
}
// packed (lo<<16)|hi
static __device__ __forceinline__ unsigned int split_pack(float x) {
  unsigned short hi, lo;
  split2(x, hi, lo);
  return ((unsigned)lo << 16) | (unsigned)hi;
}

// ---------------------------------------------------------------------------
// GEMM: C[M,N] = A[M,K] @ W[N,K]^T + bias[N]   (fp32 in/out, split-bf16 MFMA)
// Tile 128x128, BK=64, 256 threads = 4 waves, each wave 64x64 (4x4 frags).
// LDS rows padded to 72 bf16 (144 B): b128 reads aligned, lane bank stride
// 4 -> conflict-free reads; staged writes conflict-free (checked).
// ---------------------------------------------------------------------------
#define G_LDT 72

__global__ __launch_bounds__(256) void gemm_bt_split(
    const float* __restrict__ A, const float* __restrict__ W,
    const float* __restrict__ bias, float* __restrict__ C,
    int M, int N, int K) {
  __shared__ unsigned short Ahi[128][G_LDT], Alo[128][G_LDT];
  __shared__ unsigned short Bhi[128][G_LDT], Blo[128][G_LDT];

  const int t = threadIdx.x;
  const int l = t & 63;
  const int w = t >> 6;
  const int g = l >> 4;       // lane group 0..3 (k-subgroup)
  const int r16 = l & 15;     // lane within group
  const int wr = w >> 1, wc = w & 1;  // wave tile (64x64) coords in 128x128

  const int m0 = blockIdx.y * 128;
  const int n0 = blockIdx.x * 128;

  // staging coords: 16 lanes cover one 64-float row segment (256 B)
  const int srow = t >> 4;        // 0..15, +16 per pass
  const int scol = (t & 15) * 4;  // fp32 col

  f32x4 acc[4][4];
#pragma unroll
  for (int m = 0; m < 4; ++m)
#pragma unroll
    for (int n = 0; n < 4; ++n) acc[m][n] = (f32x4){0.f, 0.f, 0.f, 0.f};

  const int ksteps = K / 64;
  for (int kt = 0; kt < ksteps; ++kt) {
    // ---- stage A and W tiles (128 rows x 64 cols fp32 -> hi/lo bf16) ----
#pragma unroll
    for (int p = 0; p < 8; ++p) {
      const int row = srow + p * 16;
      fvec4 av = *reinterpret_cast<const fvec4*>(&A[(size_t)(m0 + row) * K + kt * 64 + scol]);
      fvec4 wv = *reinterpret_cast<const fvec4*>(&W[(size_t)(n0 + row) * K + kt * 64 + scol]);
      usvec4 ah, al, wh, wl;
#pragma unroll
      for (int j = 0; j < 4; ++j) {
        unsigned short h, lo;
        split2(av[j], h, lo); ah[j] = h; al[j] = lo;
        split2(wv[j], h, lo); wh[j] = h; wl[j] = lo;
      }
      *reinterpret_cast<usvec4*>(&Ahi[row][scol]) = ah;
      *reinterpret_cast<usvec4*>(&Alo[row][scol]) = al;
      *reinterpret_cast<usvec4*>(&Bhi[row][scol]) = wh;
      *reinterpret_cast<usvec4*>(&Blo[row][scol]) = wl;
    }
    __syncthreads();

    // ---- MFMA over the two 32-wide k sub-steps ----
#pragma unroll
    for (int ks = 0; ks < 2; ++ks) {
      bf16x8 ah[4], al[4], bh[4], bl[4];
#pragma unroll
      for (int m = 0; m < 4; ++m) {
        const int row = wr * 64 + m * 16 + r16;
        ah[m] = *reinterpret_cast<const bf16x8*>(&Ahi[row][ks * 32 + g * 8]);
        al[m] = *reinterpret_cast<const bf16x8*>(&Alo[row][ks * 32 + g * 8]);
      }
#pragma unroll
      for (int n = 0; n < 4; ++n) {
        const int row = wc * 64 + n * 16 + r16;
        bh[n] = *reinterpret_cast<const bf16x8*>(&Bhi[row][ks * 32 + g * 8]);
        bl[n] = *reinterpret_cast<const bf16x8*>(&Blo[row][ks * 32 + g * 8]);
      }
#pragma unroll
      for (int m = 0; m < 4; ++m)
#pragma unroll
        for (int n = 0; n < 4; ++n) {
          acc[m][n] = MFMA16(al[m], bh[n], acc[m][n]);
          acc[m][n] = MFMA16(ah[m], bl[n], acc[m][n]);
          acc[m][n] = MFMA16(ah[m], bh[n], acc[m][n]);
        }
    }
    __syncthreads();
  }

  // ---- epilogue: + bias, write fp32 (coalesced scalar stores) ----
  float bv[4];
#pragma unroll
  for (int n = 0; n < 4; ++n) bv[n] = bias[n0 + wc * 64 + n * 16 + r16];

#pragma unroll
  for (int m = 0; m < 4; ++m)
#pragma unroll
    for (int n = 0; n < 4; ++n)
#pragma unroll
      for (int r = 0; r < 4; ++r) {
        const int row = m0 + wr * 64 + m * 16 + g * 4 + r;
        const int col = n0 + wc * 64 + n * 16 + r16;
        C[(size_t)row * N + col] = acc[m][n][r] + bv[n];
      }
}

// ---------------------------------------------------------------------------
// Flash attention (per (b,h)): QBLK=64 (4 waves x 16 q-rows), KBLK=64.
// Q frags in registers (scale 1/8 folded in, exact). K staged [k][d] hi/lo.
// V: in-register 4x4 transpose (shfl_xor butterflies) -> V^T stored PACKED
// u32 (lo<<16|hi) rows [d][k], stride 68 u32 -> conflict-free b128 wr/rd.
// P round-trips per-wave LDS packed u32 (write: 2-way, read: conflict-free).
// ---------------------------------------------------------------------------
#define A_LDT 72    // bf16 row stride for K tiles (144 B)
#define V_LDT 68    // u32 row stride for Vt (272 B)
#define P_LDT 68    // u32 row stride for P (272 B)

__global__ __launch_bounds__(256) void attn_fwd_split(
    const float* Qp, const float* __restrict__ Kp,
    const float* __restrict__ Vp, float* Ctx, int S) {
  constexpr int DM = 1024, DK = 64;
  __shared__ unsigned short Khi[64][A_LDT], Klo[64][A_LDT];
  __shared__ unsigned int Vt[64][V_LDT];          // packed hi|lo, [d][k]
  __shared__ unsigned int Pint[4][16][P_LDT];     // per-wave P, packed

  const int t = threadIdx.x;
  const int l = t & 63;
  const int w = t >> 6;
  const int g = l >> 4;
  const int r16 = l & 15;

  const int b = blockIdx.z, h = blockIdx.y;
  const int q0 = blockIdx.x * 64;

  const float* Qb = Qp + (size_t)b * S * DM + h * DK;
  const float* Kb = Kp + (size_t)b * S * DM + h * DK;
  const float* Vb = Vp + (size_t)b * S * DM + h * DK;

  // ---- load Q fragments to registers (A-frag layout), fold 1/sqrt(64) ----
  bf16x8 qhi[2], qlo[2];
#pragma unroll
  for (int ks = 0; ks < 2; ++ks) {
    const float* qrow = Qb + (size_t)(q0 + w * 16 + r16) * DM + ks * 32 + g * 8;
    fvec4 x0 = *reinterpret_cast<const fvec4*>(qrow);
    fvec4 x1 = *reinterpret_cast<const fvec4*>(qrow + 4);
#pragma unroll
    for (int j = 0; j < 4; ++j) {
      unsigned short hi, lo;
      split2(x0[j] * 0.125f, hi, lo);
      qhi[ks][j] = (short)hi; qlo[ks][j] = (short)lo;
      split2(x1[j] * 0.125f, hi, lo);
      qhi[ks][4 + j] = (short)hi; qlo[ks][4 + j] = (short)lo;
    }
  }

  f32x4 o[4];
#pragma unroll
  for (int nf = 0; nf < 4; ++nf) o[nf] = (f32x4){0.f, 0.f, 0.f, 0.f};
  float mrow[4] = {-1e30f, -1e30f, -1e30f, -1e30f};
  float lrow[4] = {0.f, 0.f, 0.f, 0.f};

  const int srow = t >> 4;        // = 4*w + (l>>4); staging row 0..15
  const int scol = (t & 15) * 4;  // fp32 col in d
  const int s4 = l >> 4;          // 0..3: V-transpose quadrant
  const bool sb1 = (s4 >> 1) & 1;
  const bool sb0 = s4 & 1;

  const int ntiles = S / 64;
  for (int kt = 0; kt < ntiles; ++kt) {
    // ---- stage K (row-major hi/lo) and V (reg-transposed, packed) ----
#pragma unroll
    for (int p = 0; p < 4; ++p) {
      const int row = srow + p * 16;  // k index within tile
      fvec4 kv = *reinterpret_cast<const fvec4*>(&Kb[(size_t)(kt * 64 + row) * DM + scol]);
      fvec4 vv = *reinterpret_cast<const fvec4*>(&Vb[(size_t)(kt * 64 + row) * DM + scol]);
      usvec4 kh, kl;
      unsigned int pv0, pv1, pv2, pv3;
#pragma unroll
      for (int j = 0; j < 4; ++j) {
        unsigned short hi, lo;
        split2(kv[j], hi, lo); kh[j] = hi; kl[j] = lo;
      }
      pv0 = split_pack(vv[0]); pv1 = split_pack(vv[1]);
      pv2 = split_pack(vv[2]); pv3 = split_pack(vv[3]);
      *reinterpret_cast<usvec4*>(&Khi[row][scol]) = kh;
      *reinterpret_cast<usvec4*>(&Klo[row][scol]) = kl;

      // 4x4 transpose across s4 (lanes ^32 then ^16), elements j.
      // pv[j] holds (k = kb + s4, d = 4*r16 + j); after: (k = kb + j, d = 4*r16 + s4)
      {
        unsigned int t0 = sb1 ? pv0 : pv2;
        unsigned int t1 = sb1 ? pv1 : pv3;
        unsigned int r0 = __shfl_xor((int)t0, 32);
        unsigned int r1 = __shfl_xor((int)t1, 32);
        if (sb1) { pv0 = r0; pv1 = r1; } else { pv2 = r0; pv3 = r1; }
      }
      {
        unsigned int t0 = sb0 ? pv0 : pv1;
        unsigned int t1 = sb0 ? pv2 : pv3;
        unsigned int r0 = __shfl_xor((int)t0, 16);
        unsigned int r1 = __shfl_xor((int)t1, 16);
        if (sb0) { pv0 = r0; pv2 = r1; } else { pv1 = r0; pv3 = r1; }
      }
      const int d = 4 * r16 + s4;
      const int kb = p * 16 + w * 4;
      uvec4 out; out[0] = pv0; out[1] = pv1; out[2] = pv2; out[3] = pv3;
      *reinterpret_cast<uvec4*>(&Vt[d][kb]) = out;
    }
    __syncthreads();

    // ---- scores S = (Q/8) @ K^T : 4 n-frags x 2 ks x 3 split MFMAs ----
    f32x4 s[4];
#pragma unroll
    for (int nf = 0; nf < 4; ++nf) s[nf] = (f32x4){0.f, 0.f, 0.f, 0.f};
#pragma unroll
    for (int ks = 0; ks < 2; ++ks) {
#pragma unroll
      for (int nf = 0; nf < 4; ++nf) {
        const int row = nf * 16 + r16;
        bf16x8 kh = *reinterpret_cast<const bf16x8*>(&Khi[row][ks * 32 + g * 8]);
        bf16x8 kl = *reinterpret_cast<const bf16x8*>(&Klo[row][ks * 32 + g * 8]);
        s[nf] = MFMA16(qlo[ks], kh, s[nf]);
        s[nf] = MFMA16(qhi[ks], kl, s[nf]);
        s[nf] = MFMA16(qhi[ks], kh, s[nf]);
      }
    }

    // ---- online softmax (rows = 4*g + r; reduce over 16 lanes + 4 frags) ----
#pragma unroll
    for (int r = 0; r < 4; ++r) {
      float sm = fmaxf(fmaxf(s[0][r], s[1][r]), fmaxf(s[2][r], s[3][r]));
      sm = fmaxf(sm, __shfl_xor(sm, 1));
      sm = fmaxf(sm, __shfl_xor(sm, 2));
      sm = fmaxf(sm, __shfl_xor(sm, 4));
      sm = fmaxf(sm, __shfl_xor(sm, 8));
      const float mnew = fmaxf(mrow[r], sm);
      const float f = __expf(mrow[r] - mnew);
      mrow[r] = mnew;
      float rs = 0.f;
#pragma unroll
      for (int nf = 0; nf < 4; ++nf) {
        const float p = __expf(s[nf][r] - mnew);
        s[nf][r] = p;
        rs += p;
      }
      rs += __shfl_xor(rs, 1);
      rs += __shfl_xor(rs, 2);
      rs += __shfl_xor(rs, 4);
      rs += __shfl_xor(rs, 8);
      lrow[r] = lrow[r] * f + rs;
#pragma unroll
      for (int nf = 0; nf < 4; ++nf) o[nf][r] *= f;
    }

    // ---- write P to per-wave LDS region as packed (lo<<16 | hi) ----
#pragma unroll
    for (int nf = 0; nf < 4; ++nf)
#pragma unroll
      for (int r = 0; r < 4; ++r)
        Pint[w][g * 4 + r][nf * 16 + r16] = split_pack(s[nf][r]);
    // same-wave LDS write->read: DS ops are in program order per wave.

    // ---- PV: O += P @ V  (A = P from LDS, B = V^T packed tile) ----
#pragma unroll
    for (int ks = 0; ks < 2; ++ks) {
      uvec4 w0 = *reinterpret_cast<const uvec4*>(&Pint[w][r16][ks * 32 + g * 8]);
      uvec4 w1 = *reinterpret_cast<const uvec4*>(&Pint[w][r16][ks * 32 + g * 8 + 4]);
      bf16x8 ph, pl;
#pragma unroll
      for (int j = 0; j < 4; ++j) {
        ph[j] = (short)(w0[j] & 0xFFFFu); pl[j] = (short)(w0[j] >> 16);
        ph[4 + j] = (short)(w1[j] & 0xFFFFu); pl[4 + j] = (short)(w1[j] >> 16);
      }
#pragma unroll
      for (int nf = 0; nf < 4; ++nf) {
        const int vrow = nf * 16 + r16;  // d index
        uvec4 u0 = *reinterpret_cast<const uvec4*>(&Vt[vrow][ks * 32 + g * 8]);
        uvec4 u1 = *reinterpret_cast<const uvec4*>(&Vt[vrow][ks * 32 + g * 8 + 4]);
        bf16x8 vh, vl;
#pragma unroll
        for (int j = 0; j < 4; ++j) {
          vh[j] = (short)(u0[j] & 0xFFFFu); vl[j] = (short)(u0[j] >> 16);
          vh[4 + j] = (short)(u1[j] & 0xFFFFu); vl[4 + j] = (short)(u1[j] >> 16);
        }
        o[nf] = MFMA16(pl, vh, o[nf]);
        o[nf] = MFMA16(ph, vl, o[nf]);
        o[nf] = MFMA16(ph, vh, o[nf]);
      }
    }
    __syncthreads();  // all K/Vt/P reads done before next staging
  }

  // ---- epilogue: O / l, write Ctx[b, q, h*64 + d] ----
#pragma unroll
  for (int r = 0; r < 4; ++r) {
    const float inv = 1.0f / lrow[r];
    const int row = q0 + w * 16 + g * 4 + r;
#pragma unroll
    for (int nf = 0; nf < 4; ++nf) {
      Ctx[((size_t)b * S + row) * DM + h * DK + nf * 16 + r16] = o[nf][r] * inv;
    }
  }
}

// ---------------------------------------------------------------------------
extern "C" void kernel_launch(void* const* d_in, const int* in_sizes, int n_in,
                              void* d_out, int out_size, void* d_ws, size_t ws_size,
                              hipStream_t stream) {
  const float* q  = (const float*)d_in[0];
  const float* k  = (const float*)d_in[1];
  const float* v  = (const float*)d_in[2];
  const float* Wq = (const float*)d_in[3];
  const float* bq = (const float*)d_in[4];
  const float* Wk = (const float*)d_in[5];
  const float* bk = (const float*)d_in[6];
  const float* Wv = (const float*)d_in[7];
  const float* bv = (const float*)d_in[8];
  const float* Wo = (const float*)d_in[9];
  const float* bo = (const float*)d_in[10];

  const int DM = 1024;
  const int S = 2048;
  const int BS = in_sizes[0] / DM;  // B*S = 8192
  const int B = BS / S;

  float* ws = (float*)d_ws;
  const size_t sz = (size_t)BS * DM;
  float* Qp  = ws;            // also reused as Ctx (see attn kernel header)
  float* Kpj = ws + sz;
  float* Vpj = ws + 2 * sz;
  float* Ctx = Qp;            // alias: saves 32 MB of workspace

  dim3 ggrid(DM / 128, BS / 128);  // (8, 64)
  gemm_bt_split<<<ggrid, 256, 0, stream>>>(q, Wq, bq, Qp,  BS, DM, DM);
  gemm_bt_split<<<ggrid, 256, 0, stream>>>(k, Wk, bk, Kpj, BS, DM, DM);
  gemm_bt_split<<<ggrid, 256, 0, stream>>>(v, Wv, bv, Vpj, BS, DM, DM);

  attn_fwd_split<<<dim3(S / 64, 16, B), 256, 0, stream>>>(Qp, Kpj, Vpj, Ctx, S);

  gemm_bt_split<<<ggrid, 256, 0, stream>>>(Ctx, Wo, bo, (float*)d_out, BS, DM, DM);
}

// Round 4
// 966.431 us; speedup vs baseline: 1.1025x; 1.1025x over previous
//
#include <hip/hip_runtime.h>
#include <hip/hip_bf16.h>

// MHA forward, fp32 I/O, MI355X (gfx950).
// All matmuls via bf16 split-precision MFMA (x = hi + lo bf16;
// x*y ~= hi*hi + hi*lo + lo*hi, fp32 accum). No fp32-input MFMA on CDNA4.
//
// R4 vs R3 (R3 never ran; R2 measured attn 560us MfmaUtil 16%, VALUBusy 65%,
// LDS_BANK_CONFLICT 6.3e7):
//  - LDS: padding replaced by 16B-slot XOR swizzle (slot ^= row&7) on 128B
//    rows. R2/R3's 144B-row padding made every frag ds_read_b128 an 8-way
//    bank conflict (row shift 4 dwords); swizzle makes all staged accesses
//    minimum-aliasing. Applies to GEMM A/B planes, K planes, V^T, P planes.
//  - Pre-split pipeline: q/k/v packed once (ws>=144MB), weights split once
//    (ws>=112MB), attention emits packed Ctx always -> GEMM staging is
//    copy+unpack instead of fp32->split (was the VALU bottleneck).
//  - Attention QBLK=128: 2 q-groups per wave share one K/V staging+transpose.
// All numerics bit-identical to R2/R3 (same split2 on same values).

typedef __attribute__((ext_vector_type(8))) short bf16x8;
typedef __attribute__((ext_vector_type(4))) float f32x4;
typedef __attribute__((ext_vector_type(4))) float fvec4;
typedef __attribute__((ext_vector_type(4))) unsigned int uvec4;
typedef __attribute__((ext_vector_type(4))) unsigned short usvec4;

#define MFMA16(a, b, c) __builtin_amdgcn_mfma_f32_16x16x32_bf16((a), (b), (c), 0, 0, 0)

static __device__ __forceinline__ unsigned short f2bf(float f) {
  unsigned u = __builtin_bit_cast(unsigned, f);
  unsigned r = u + 0x7FFFu + ((u >> 16) & 1u);  // RNE
  return (unsigned short)(r >> 16);
}
static __device__ __forceinline__ float bf2f(unsigned short h) {
  unsigned u = ((unsigned)h) << 16;
  return __builtin_bit_cast(float, u);
}
static __device__ __forceinline__ void split2(float x, unsigned short& hi, unsigned short& lo) {
  hi = f2bf(x);
  lo = f2bf(x - bf2f(hi));
}
static __device__ __forceinline__ unsigned int split_pack(float x) {
  unsigned short hi, lo;
  split2(x, hi, lo);
  return ((unsigned)lo << 16) | (unsigned)hi;
}

// Swizzled index into a [R][64]-ushort (128B-row) LDS plane.
// 16B slot s of row r lives at slot (s ^ (r&7)). Keeps b128 reads aligned;
// 8B sub-accesses (col_us % 8 in {0,4}) stay inside one slot.
static __device__ __forceinline__ int swz(int row, int col_us) {
  return (row << 6) + (((( col_us >> 3) ^ row) & 7) << 3) + (col_us & 7);
}

// ---------------------------------------------------------------------------
// One-time converters (memory-bound).
// ---------------------------------------------------------------------------
__global__ __launch_bounds__(256) void convert_split(
    const float* __restrict__ in, unsigned short* __restrict__ hp,
    unsigned short* __restrict__ lp, int n) {
  const int i = (blockIdx.x * 256 + threadIdx.x) * 4;
  if (i >= n) return;
  fvec4 x = *reinterpret_cast<const fvec4*>(&in[i]);
  usvec4 h, l;
#pragma unroll
  for (int j = 0; j < 4; ++j) {
    unsigned short hi, lo;
    split2(x[j], hi, lo);
    h[j] = hi; l[j] = lo;
  }
  *reinterpret_cast<usvec4*>(&hp[i]) = h;
  *reinterpret_cast<usvec4*>(&lp[i]) = l;
}

__global__ __launch_bounds__(256) void convert_pack(
    const float* __restrict__ in, unsigned int* __restrict__ out, int n) {
  const int i = (blockIdx.x * 256 + threadIdx.x) * 4;
  if (i >= n) return;
  fvec4 x = *reinterpret_cast<const fvec4*>(&in[i]);
  uvec4 o;
#pragma unroll
  for (int j = 0; j < 4; ++j) o[j] = split_pack(x[j]);
  *reinterpret_cast<uvec4*>(&out[i]) = o;
}

// ---------------------------------------------------------------------------
// GEMM: C[M,N] = A[M,K] @ W[N,K]^T + bias[N]
// Tile 128x128, BK=64, 4 waves of 64x64 (4x4 16x16 frags).
// AMODE: 0 = A fp32 (split in-kernel), 1 = A packed u32 (lo<<16|hi).
// BMODE: 0 = B fp32 (split in-kernel), 1 = B pre-split hi/lo planes.
// OMODE: 0 = fp32 out, 1 = packed u32 out, 2 = packed u32, scaled 0.125 (Q).
// ---------------------------------------------------------------------------
template <int AMODE, int BMODE, int OMODE>
__global__ __launch_bounds__(256) void gemm_k(
    const void* __restrict__ Ap, const void* __restrict__ Bp0,
    const void* __restrict__ Bp1, const float* __restrict__ bias,
    void* __restrict__ Cout, int M, int N, int K) {
  __shared__ unsigned short Ahi[128 * 64], Alo[128 * 64];
  __shared__ unsigned short Bhi[128 * 64], Blo[128 * 64];

  const int t = threadIdx.x;
  const int l = t & 63;
  const int w = t >> 6;
  const int g = l >> 4;
  const int r16 = l & 15;
  const int wr = w >> 1, wc = w & 1;

  const int m0 = blockIdx.y * 128;
  const int n0 = blockIdx.x * 128;

  const int srow = t >> 4;         // 0..15 per pass
  const int scol = (t & 15) * 4;   // element col (fp32/packed/bf16 units)

  f32x4 acc[4][4];
#pragma unroll
  for (int m = 0; m < 4; ++m)
#pragma unroll
    for (int n = 0; n < 4; ++n) acc[m][n] = (f32x4){0.f, 0.f, 0.f, 0.f};

  const int ksteps = K / 64;
  for (int kt = 0; kt < ksteps; ++kt) {
    // ---- stage A and B tiles into swizzled hi/lo planes ----
#pragma unroll
    for (int p = 0; p < 8; ++p) {
      const int row = srow + p * 16;
      usvec4 ah, al, bh, bl;
      if constexpr (AMODE == 0) {
        fvec4 av = *reinterpret_cast<const fvec4*>(
            &((const float*)Ap)[(size_t)(m0 + row) * K + kt * 64 + scol]);
#pragma unroll
        for (int j = 0; j < 4; ++j) {
          unsigned short h, lo;
          split2(av[j], h, lo);
          ah[j] = h; al[j] = lo;
        }
      } else {
        uvec4 av = *reinterpret_cast<const uvec4*>(
            &((const unsigned int*)Ap)[(size_t)(m0 + row) * K + kt * 64 + scol]);
#pragma unroll
        for (int j = 0; j < 4; ++j) {
          ah[j] = (unsigned short)(av[j] & 0xFFFFu);
          al[j] = (unsigned short)(av[j] >> 16);
        }
      }
      if constexpr (BMODE == 0) {
        fvec4 wv = *reinterpret_cast<const fvec4*>(
            &((const float*)Bp0)[(size_t)(n0 + row) * K + kt * 64 + scol]);
#pragma unroll
        for (int j = 0; j < 4; ++j) {
          unsigned short h, lo;
          split2(wv[j], h, lo);
          bh[j] = h; bl[j] = lo;
        }
      } else {
        bh = *reinterpret_cast<const usvec4*>(
            &((const unsigned short*)Bp0)[(size_t)(n0 + row) * K + kt * 64 + scol]);
        bl = *reinterpret_cast<const usvec4*>(
            &((const unsigned short*)Bp1)[(size_t)(n0 + row) * K + kt * 64 + scol]);
      }
      const int o = swz(row, scol);
      *reinterpret_cast<usvec4*>(&Ahi[o]) = ah;
      *reinterpret_cast<usvec4*>(&Alo[o]) = al;
      *reinterpret_cast<usvec4*>(&Bhi[o]) = bh;
      *reinterpret_cast<usvec4*>(&Blo[o]) = bl;
    }
    __syncthreads();

    // ---- MFMA over the two 32-wide k sub-steps ----
#pragma unroll
    for (int ks = 0; ks < 2; ++ks) {
      bf16x8 ah[4], al[4], bh[4], bl[4];
#pragma unroll
      for (int m = 0; m < 4; ++m) {
        const int o = swz(wr * 64 + m * 16 + r16, ks * 32 + g * 8);
        ah[m] = *reinterpret_cast<const bf16x8*>(&Ahi[o]);
        al[m] = *reinterpret_cast<const bf16x8*>(&Alo[o]);
      }
#pragma unroll
      for (int n = 0; n < 4; ++n) {
        const int o = swz(wc * 64 + n * 16 + r16, ks * 32 + g * 8);
        bh[n] = *reinterpret_cast<const bf16x8*>(&Bhi[o]);
        bl[n] = *reinterpret_cast<const bf16x8*>(&Blo[o]);
      }
#pragma unroll
      for (int m = 0; m < 4; ++m)
#pragma unroll
        for (int n = 0; n < 4; ++n) {
          acc[m][n] = MFMA16(al[m], bh[n], acc[m][n]);
          acc[m][n] = MFMA16(ah[m], bl[n], acc[m][n]);
          acc[m][n] = MFMA16(ah[m], bh[n], acc[m][n]);
        }
    }
    __syncthreads();
  }

  // ---- epilogue ----
  float bv[4];
#pragma unroll
  for (int n = 0; n < 4; ++n) bv[n] = bias[n0 + wc * 64 + n * 16 + r16];

#pragma unroll
  for (int m = 0; m < 4; ++m)
#pragma unroll
    for (int n = 0; n < 4; ++n)
#pragma unroll
      for (int r = 0; r < 4; ++r) {
        const int row = m0 + wr * 64 + m * 16 + g * 4 + r;
        const int col = n0 + wc * 64 + n * 16 + r16;
        const float c = acc[m][n][r] + bv[n];
        if constexpr (OMODE == 0) {
          ((float*)Cout)[(size_t)row * N + col] = c;
        } else if constexpr (OMODE == 1) {
          ((unsigned int*)Cout)[(size_t)row * N + col] = split_pack(c);
        } else {
          ((unsigned int*)Cout)[(size_t)row * N + col] = split_pack(c * 0.125f);
        }
      }
}

// ---------------------------------------------------------------------------
// Flash attention (per (b,h)): QBLK=128 (4 waves x 2 q-groups x 16 rows),
// KBLK=64. Q frags in registers (1/8 pre-folded by GEMM OMODE=2). K staged
// as hi/lo planes; V reg-transposed (shfl_xor 4x4) into V^T hi/lo planes;
// P round-trips per-wave hi/lo planes. All LDS accesses XOR-swizzled.
// Output written PACKED (split u32) for the final GEMM; Ctx aliases Qpk
// (each block reads exactly the Q cells it later writes; reads precede
// writes; blocks partition (q0,h,b) disjointly).
// ---------------------------------------------------------------------------
__global__ __launch_bounds__(256) void attn_fwd(
    const unsigned int* Qpk, const unsigned int* __restrict__ Kpk,
    const unsigned int* __restrict__ Vpk, unsigned int* CtxPk, int S) {
  constexpr int DM = 1024, DK = 64;
  __shared__ unsigned short Khi[64 * 64], Klo[64 * 64];
  __shared__ unsigned short Vth[64 * 64], Vtl[64 * 64];
  __shared__ unsigned short Ph[4 * 16 * 64], Pl[4 * 16 * 64];

  const int t = threadIdx.x;
  const int l = t & 63;
  const int w = t >> 6;
  const int g = l >> 4;
  const int r16 = l & 15;
  const int pw = w << 10;  // per-wave P plane base (16*64 ushorts)

  const int b = blockIdx.z, h = blockIdx.y;
  const int q0 = blockIdx.x * 128;

  // ---- Q fragments for both q-groups (packed, pre-scaled by 1/8) ----
  bf16x8 qhi[2][2], qlo[2][2];
#pragma unroll
  for (int qq = 0; qq < 2; ++qq)
#pragma unroll
    for (int ks = 0; ks < 2; ++ks) {
      const unsigned int* qrow =
          &Qpk[(size_t)(b * S + q0 + qq * 64 + w * 16 + r16) * DM + h * DK + ks * 32 + g * 8];
      uvec4 u0 = *reinterpret_cast<const uvec4*>(qrow);
      uvec4 u1 = *reinterpret_cast<const uvec4*>(qrow + 4);
#pragma unroll
      for (int j = 0; j < 4; ++j) {
        qhi[qq][ks][j] = (short)(u0[j] & 0xFFFFu);
        qlo[qq][ks][j] = (short)(u0[j] >> 16);
        qhi[qq][ks][4 + j] = (short)(u1[j] & 0xFFFFu);
        qlo[qq][ks][4 + j] = (short)(u1[j] >> 16);
      }
    }

  f32x4 o[2][4];
#pragma unroll
  for (int qq = 0; qq < 2; ++qq)
#pragma unroll
    for (int nf = 0; nf < 4; ++nf) o[qq][nf] = (f32x4){0.f, 0.f, 0.f, 0.f};
  float mrow[2][4], lrow[2][4];
#pragma unroll
  for (int qq = 0; qq < 2; ++qq)
#pragma unroll
    for (int r = 0; r < 4; ++r) { mrow[qq][r] = -1e30f; lrow[qq][r] = 0.f; }

  const int srow = t >> 4;        // staging k-row 0..15 (+16/pass)
  const int scol = (t & 15) * 4;  // element col in d
  const int s4 = l >> 4;          // V-transpose quadrant
  const bool sb1 = (s4 >> 1) & 1;
  const bool sb0 = s4 & 1;

  const int ntiles = S / 64;
  for (int kt = 0; kt < ntiles; ++kt) {
    // ---- stage K (unpack to planes) and V (reg-transpose 4x4, unpack) ----
#pragma unroll
    for (int p = 0; p < 4; ++p) {
      const int row = srow + p * 16;  // k index within tile
      const size_t gbase = (size_t)(b * S + kt * 64 + row) * DM + h * DK + scol;
      uvec4 kv = *reinterpret_cast<const uvec4*>(&Kpk[gbase]);
      uvec4 vv = *reinterpret_cast<const uvec4*>(&Vpk[gbase]);
      usvec4 kh, kl;
#pragma unroll
      for (int j = 0; j < 4; ++j) {
        kh[j] = (unsigned short)(kv[j] & 0xFFFFu);
        kl[j] = (unsigned short)(kv[j] >> 16);
      }
      const int ko = swz(row, scol);
      *reinterpret_cast<usvec4*>(&Khi[ko]) = kh;
      *reinterpret_cast<usvec4*>(&Klo[ko]) = kl;

      // 4x4 transpose across s4 (lanes ^32 then ^16), packed u32 elements.
      // before: lane holds (k = kb+s4, d = 4*r16+j); after: (k = kb+j, d = 4*r16+s4)
      unsigned int pv0 = vv[0], pv1 = vv[1], pv2 = vv[2], pv3 = vv[3];
      {
        unsigned int t0 = sb1 ? pv0 : pv2;
        unsigned int t1 = sb1 ? pv1 : pv3;
        unsigned int r0 = __shfl_xor((int)t0, 32);
        unsigned int r1 = __shfl_xor((int)t1, 32);
        if (sb1) { pv0 = r0; pv1 = r1; } else { pv2 = r0; pv3 = r1; }
      }
      {
        unsigned int t0 = sb0 ? pv0 : pv1;
        unsigned int t1 = sb0 ? pv2 : pv3;
        unsigned int r0 = __shfl_xor((int)t0, 16);
        unsigned int r1 = __shfl_xor((int)t1, 16);
        if (sb0) { pv0 = r0; pv2 = r1; } else { pv1 = r0; pv3 = r1; }
      }
      const int d = 4 * r16 + s4;
      const int kb = p * 16 + w * 4;
      usvec4 vh, vl;
      vh[0] = (unsigned short)(pv0 & 0xFFFFu); vl[0] = (unsigned short)(pv0 >> 16);
      vh[1] = (unsigned short)(pv1 & 0xFFFFu); vl[1] = (unsigned short)(pv1 >> 16);
      vh[2] = (unsigned short)(pv2 & 0xFFFFu); vl[2] = (unsigned short)(pv2 >> 16);
      vh[3] = (unsigned short)(pv3 & 0xFFFFu); vl[3] = (unsigned short)(pv3 >> 16);
      const int vo = swz(d, kb);
      *reinterpret_cast<usvec4*>(&Vth[vo]) = vh;
      *reinterpret_cast<usvec4*>(&Vtl[vo]) = vl;
    }
    __syncthreads();

#pragma unroll
    for (int qq = 0; qq < 2; ++qq) {
      // ---- scores S = (Q/8) @ K^T ----
      f32x4 s[4];
#pragma unroll
      for (int nf = 0; nf < 4; ++nf) s[nf] = (f32x4){0.f, 0.f, 0.f, 0.f};
#pragma unroll
      for (int ks = 0; ks < 2; ++ks) {
#pragma unroll
        for (int nf = 0; nf < 4; ++nf) {
          const int o2 = swz(nf * 16 + r16, ks * 32 + g * 8);
          bf16x8 kh = *reinterpret_cast<const bf16x8*>(&Khi[o2]);
          bf16x8 kl = *reinterpret_cast<const bf16x8*>(&Klo[o2]);
          s[nf] = MFMA16(qlo[qq][ks], kh, s[nf]);
          s[nf] = MFMA16(qhi[qq][ks], kl, s[nf]);
          s[nf] = MFMA16(qhi[qq][ks], kh, s[nf]);
        }
      }

      // ---- online softmax (rows = 4*g + r; 16-lane + 4-frag reduce) ----
#pragma unroll
      for (int r = 0; r < 4; ++r) {
        float sm = fmaxf(fmaxf(s[0][r], s[1][r]), fmaxf(s[2][r], s[3][r]));
        sm = fmaxf(sm, __shfl_xor(sm, 1));
        sm = fmaxf(sm, __shfl_xor(sm, 2));
        sm = fmaxf(sm, __shfl_xor(sm, 4));
        sm = fmaxf(sm, __shfl_xor(sm, 8));
        const float mnew = fmaxf(mrow[qq][r], sm);
        const float f = __expf(mrow[qq][r] - mnew);
        mrow[qq][r] = mnew;
        float rs = 0.f;
#pragma unroll
        for (int nf = 0; nf < 4; ++nf) {
          const float p = __expf(s[nf][r] - mnew);
          s[nf][r] = p;
          rs += p;
        }
        rs += __shfl_xor(rs, 1);
        rs += __shfl_xor(rs, 2);
        rs += __shfl_xor(rs, 4);
        rs += __shfl_xor(rs, 8);
        lrow[qq][r] = lrow[qq][r] * f + rs;
#pragma unroll
        for (int nf = 0; nf < 4; ++nf) o[qq][nf][r] *= f;
      }

      // ---- write P to per-wave swizzled hi/lo planes ----
#pragma unroll
      for (int nf = 0; nf < 4; ++nf)
#pragma unroll
        for (int r = 0; r < 4; ++r) {
          unsigned short hi, lo;
          split2(s[nf][r], hi, lo);
          const int po = pw + swz(g * 4 + r, nf * 16 + r16);
          Ph[po] = hi;
          Pl[po] = lo;
        }
      // same-wave LDS write->read: DS ops are in program order per wave.

      // ---- PV: O += P @ V (direct b128 frag reads from planes) ----
#pragma unroll
      for (int ks = 0; ks < 2; ++ks) {
        const int po = pw + swz(r16, ks * 32 + g * 8);
        bf16x8 ph = *reinterpret_cast<const bf16x8*>(&Ph[po]);
        bf16x8 pl = *reinterpret_cast<const bf16x8*>(&Pl[po]);
#pragma unroll
        for (int nf = 0; nf < 4; ++nf) {
          const int vo = swz(nf * 16 + r16, ks * 32 + g * 8);
          bf16x8 vh = *reinterpret_cast<const bf16x8*>(&Vth[vo]);
          bf16x8 vl = *reinterpret_cast<const bf16x8*>(&Vtl[vo]);
          o[qq][nf] = MFMA16(pl, vh, o[qq][nf]);
          o[qq][nf] = MFMA16(ph, vl, o[qq][nf]);
          o[qq][nf] = MFMA16(ph, vh, o[qq][nf]);
        }
      }
    }
    __syncthreads();
  }

  // ---- epilogue: pack O / l, write CtxPk (aliases Qpk; see header) ----
#pragma unroll
  for (int qq = 0; qq < 2; ++qq)
#pragma unroll
    for (int r = 0; r < 4; ++r) {
      const float inv = 1.0f / lrow[qq][r];
      const int row = q0 + qq * 64 + w * 16 + g * 4 + r;
#pragma unroll
      for (int nf = 0; nf < 4; ++nf) {
        CtxPk[((size_t)b * S + row) * DM + h * DK + nf * 16 + r16] =
            split_pack(o[qq][nf][r] * inv);
      }
    }
}

// ---------------------------------------------------------------------------
extern "C" void kernel_launch(void* const* d_in, const int* in_sizes, int n_in,
                              void* d_out, int out_size, void* d_ws, size_t ws_size,
                              hipStream_t stream) {
  const float* q  = (const float*)d_in[0];
  const float* k  = (const float*)d_in[1];
  const float* v  = (const float*)d_in[2];
  const float* Wq = (const float*)d_in[3];
  const float* bq = (const float*)d_in[4];
  const float* Wk = (const float*)d_in[5];
  const float* bk = (const float*)d_in[6];
  const float* Wv = (const float*)d_in[7];
  const float* bv = (const float*)d_in[8];
  const float* Wo = (const float*)d_in[9];
  const float* bo = (const float*)d_in[10];

  const int DM = 1024;
  const int S = 2048;
  const int BS = in_sizes[0] / DM;  // B*S = 8192
  const int B = BS / S;
  const size_t MB = 1024 * 1024;

  const int NW = DM * DM;               // weight elements
  const int NI = BS * DM;               // per-input elements
  const int cgW = NW / (256 * 4);
  const int cgI = NI / (256 * 4);
  dim3 ggrid(DM / 128, BS / 128);       // (8, 64)
  dim3 agrid(S / 128, 16, B);           // QBLK=128

  char* wsb = (char*)d_ws;

  if (ws_size >= 144 * MB) {
    // FULL: T | Qpk | Kpk | Vpk | Wplanes
    unsigned int* T   = (unsigned int*)(wsb);
    unsigned int* Qpk = (unsigned int*)(wsb + 32 * MB);
    unsigned int* Kpk = (unsigned int*)(wsb + 64 * MB);
    unsigned int* Vpk = (unsigned int*)(wsb + 96 * MB);
    unsigned short* Wp = (unsigned short*)(wsb + 128 * MB);
    unsigned short *Wqh = Wp + 0 * MB, *Wql = Wp + 1 * MB;
    unsigned short *Wkh = Wp + 2 * MB, *Wkl = Wp + 3 * MB;
    unsigned short *Wvh = Wp + 4 * MB, *Wvl = Wp + 5 * MB;
    unsigned short *Woh = Wp + 6 * MB, *Wol = Wp + 7 * MB;

    convert_split<<<cgW, 256, 0, stream>>>(Wq, Wqh, Wql, NW);
    convert_split<<<cgW, 256, 0, stream>>>(Wk, Wkh, Wkl, NW);
    convert_split<<<cgW, 256, 0, stream>>>(Wv, Wvh, Wvl, NW);
    convert_split<<<cgW, 256, 0, stream>>>(Wo, Woh, Wol, NW);

    convert_pack<<<cgI, 256, 0, stream>>>(q, T, NI);
    gemm_k<1, 1, 2><<<ggrid, 256, 0, stream>>>(T, Wqh, Wql, bq, Qpk, BS, DM, DM);
    convert_pack<<<cgI, 256, 0, stream>>>(k, T, NI);
    gemm_k<1, 1, 1><<<ggrid, 256, 0, stream>>>(T, Wkh, Wkl, bk, Kpk, BS, DM, DM);
    convert_pack<<<cgI, 256, 0, stream>>>(v, T, NI);
    gemm_k<1, 1, 1><<<ggrid, 256, 0, stream>>>(T, Wvh, Wvl, bv, Vpk, BS, DM, DM);

    attn_fwd<<<agrid, 256, 0, stream>>>(Qpk, Kpk, Vpk, Qpk, S);

    gemm_k<1, 1, 0><<<ggrid, 256, 0, stream>>>(Qpk, Woh, Wol, bo, d_out, BS, DM, DM);
  } else if (ws_size >= 112 * MB) {
    // MID: Qpk | Kpk | Vpk | Wplanes (A staged fp32 in-kernel for QKV)
    unsigned int* Qpk = (unsigned int*)(wsb);
    unsigned int* Kpk = (unsigned int*)(wsb + 32 * MB);
    unsigned int* Vpk = (unsigned int*)(wsb + 64 * MB);
    unsigned short* Wp = (unsigned short*)(wsb + 96 * MB);
    unsigned short *Wqh = Wp + 0 * MB, *Wql = Wp + 1 * MB;
    unsigned short *Wkh = Wp + 2 * MB, *Wkl = Wp + 3 * MB;
    unsigned short *Wvh = Wp + 4 * MB, *Wvl = Wp + 5 * MB;
    unsigned short *Woh = Wp + 6 * MB, *Wol = Wp + 7 * MB;

    convert_split<<<cgW, 256, 0, stream>>>(Wq, Wqh, Wql, NW);
    convert_split<<<cgW, 256, 0, stream>>>(Wk, Wkh, Wkl, NW);
    convert_split<<<cgW, 256, 0, stream>>>(Wv, Wvh, Wvl, NW);
    convert_split<<<cgW, 256, 0, stream>>>(Wo, Woh, Wol, NW);

    gemm_k<0, 1, 2><<<ggrid, 256, 0, stream>>>(q, Wqh, Wql, bq, Qpk, BS, DM, DM);
    gemm_k<0, 1, 1><<<ggrid, 256, 0, stream>>>(k, Wkh, Wkl, bk, Kpk, BS, DM, DM);
    gemm_k<0, 1, 1><<<ggrid, 256, 0, stream>>>(v, Wvh, Wvl, bv, Vpk, BS, DM, DM);

    attn_fwd<<<agrid, 256, 0, stream>>>(Qpk, Kpk, Vpk, Qpk, S);

    gemm_k<1, 1, 0><<<ggrid, 256, 0, stream>>>(Qpk, Woh, Wol, bo, d_out, BS, DM, DM);
  } else {
    // MIN (96 MB, hardware-proven): no pre-split weights.
    unsigned int* Qpk = (unsigned int*)(wsb);
    unsigned int* Kpk = (unsigned int*)(wsb + 32 * MB);
    unsigned int* Vpk = (unsigned int*)(wsb + 64 * MB);

    gemm_k<0, 0, 2><<<ggrid, 256, 0, stream>>>(q, Wq, nullptr, bq, Qpk, BS, DM, DM);
    gemm_k<0, 0, 1><<<ggrid, 256, 0, stream>>>(k, Wk, nullptr, bk, Kpk, BS, DM, DM);
    gemm_k<0, 0, 1><<<ggrid, 256, 0, stream>>>(v, Wv, nullptr, bv, Vpk, BS, DM, DM);

    attn_fwd<<<agrid, 256, 0, stream>>>(Qpk, Kpk, Vpk, Qpk, S);

    gemm_k<1, 0, 0><<<ggrid, 256, 0, stream>>>(Qpk, Wo, nullptr, bo, d_out, BS, DM, DM);
  }
}

// Round 7
// 766.415 us; speedup vs baseline: 1.3902x; 1.2610x over previous
//
#include <hip/hip_runtime.h>
#include <hip/hip_bf16.h>

// MHA forward, fp32 I/O, MI355X (gfx950).
// All matmuls via bf16 split-precision MFMA (x = hi + lo bf16;
// x*y ~= hi*hi + hi*lo + lo*hi, fp32 accum). No fp32-input MFMA on CDNA4.
//
// R7 = R5/R6 resubmitted (neither ran: GPU acquisition timeouts).
// vs R4 (measured: total 966us; attn 529us MfmaUtil 16.6% VALUBusy 36%
// OccupancyPercent 22.6% -> latency-bound; GEMMs ~109us each):
//  - GEMM staging via global_load_lds width=16 of pre-split bf16 planes,
//    pre-swizzled GLOBAL source + swizzled LDS reads (rule #21 both-sides).
//    FULL tier: A and B planes; MID tier: B planes only.
//  - Attention: async-STAGE split (T14) - next tile's global loads issued
//    before current tile's compute; unpack/transpose/ds_write after the
//    post-compute barrier. Plus s_setprio(1) around MFMA clusters (T5).
// All numerics bit-identical to R2/R3/R4 (same split2 on same values).

typedef __attribute__((ext_vector_type(8))) short bf16x8;
typedef __attribute__((ext_vector_type(4))) float f32x4;
typedef __attribute__((ext_vector_type(4))) float fvec4;
typedef __attribute__((ext_vector_type(4))) unsigned int uvec4;
typedef __attribute__((ext_vector_type(4))) unsigned short usvec4;

#define MFMA16(a, b, c) __builtin_amdgcn_mfma_f32_16x16x32_bf16((a), (b), (c), 0, 0, 0)

static __device__ __forceinline__ unsigned short f2bf(float f) {
  unsigned u = __builtin_bit_cast(unsigned, f);
  unsigned r = u + 0x7FFFu + ((u >> 16) & 1u);  // RNE
  return (unsigned short)(r >> 16);
}
static __device__ __forceinline__ float bf2f(unsigned short h) {
  unsigned u = ((unsigned)h) << 16;
  return __builtin_bit_cast(float, u);
}
static __device__ __forceinline__ void split2(float x, unsigned short& hi, unsigned short& lo) {
  hi = f2bf(x);
  lo = f2bf(x - bf2f(hi));
}
static __device__ __forceinline__ unsigned int split_pack(float x) {
  unsigned short hi, lo;
  split2(x, hi, lo);
  return ((unsigned)lo << 16) | (unsigned)hi;
}

// Swizzled index into a [R][64]-ushort (128B-row) LDS plane.
// 16B slot s of row r lives at physical slot (s ^ (r&7)).
static __device__ __forceinline__ int swz(int row, int col_us) {
  return (row << 6) + ((((col_us >> 3) ^ row) & 7) << 3) + (col_us & 7);
}

// Async global->LDS, 16B per lane. LDS dest must be wave-uniform base
// (HW writes lane i at base + i*16). Global src is per-lane.
static __device__ __forceinline__ void glds16(const void* g, void* l) {
  __builtin_amdgcn_global_load_lds(
      (const __attribute__((address_space(1))) void*)g,
      (__attribute__((address_space(3))) void*)l, 16, 0, 0);
}

// ---------------------------------------------------------------------------
// One-time converter: fp32 -> hi/lo bf16 planes (memory-bound).
// ---------------------------------------------------------------------------
__global__ __launch_bounds__(256) void convert_split(
    const float* __restrict__ in, unsigned short* __restrict__ hp,
    unsigned short* __restrict__ lp, int n) {
  const int i = (blockIdx.x * 256 + threadIdx.x) * 4;
  if (i >= n) return;
  fvec4 x = *reinterpret_cast<const fvec4*>(&in[i]);
  usvec4 h, l;
#pragma unroll
  for (int j = 0; j < 4; ++j) {
    unsigned short hi, lo;
    split2(x[j], hi, lo);
    h[j] = hi; l[j] = lo;
  }
  *reinterpret_cast<usvec4*>(&hp[i]) = h;
  *reinterpret_cast<usvec4*>(&lp[i]) = l;
}

// ---------------------------------------------------------------------------
// GEMM: C[M,N] = A[M,K] @ W[N,K]^T + bias[N]
// Tile 128x128, BK=64, 4 waves of 64x64 (4x4 16x16x32 frags), swizzled LDS.
// AMODE: 0 = A fp32 (split in-kernel, reg-staged)
//        1 = A packed u32 (unpack, reg-staged)
//        2 = A pre-split hi/lo planes (global_load_lds, pre-swizzled source)
// BMODE: 0 = B fp32 (reg-staged)   1 = B planes (global_load_lds)
// OMODE: 0 = fp32 out, 1 = packed u32 out, 2 = packed u32 scaled 0.125 (Q).
// ---------------------------------------------------------------------------
template <int AMODE, int BMODE, int OMODE>
__global__ __launch_bounds__(256) void gemm_k(
    const void* __restrict__ Ap0, const void* __restrict__ Ap1,
    const void* __restrict__ Bp0, const void* __restrict__ Bp1,
    const float* __restrict__ bias, void* __restrict__ Cout,
    int M, int N, int K) {
  __shared__ unsigned short Ahi[128 * 64], Alo[128 * 64];
  __shared__ unsigned short Bhi[128 * 64], Blo[128 * 64];

  const int t = threadIdx.x;
  const int l = t & 63;
  const int w = t >> 6;
  const int g = l >> 4;
  const int r16 = l & 15;
  const int wr = w >> 1, wc = w & 1;

  const int m0 = blockIdx.y * 128;
  const int n0 = blockIdx.x * 128;

  const int srow = t >> 4;         // reg-staging row 0..15 per pass
  const int scol = (t & 15) * 4;   // element col
  // glds lane coords: 8 rows x 8 slots of 16B per wave-call
  const int glrow = l >> 3;                    // row within 8-row chunk
  const int glcol = ((l & 7) ^ glrow) * 8;     // pre-swizzled source col (us)

  f32x4 acc[4][4];
#pragma unroll
  for (int m = 0; m < 4; ++m)
#pragma unroll
    for (int n = 0; n < 4; ++n) acc[m][n] = (f32x4){0.f, 0.f, 0.f, 0.f};

  const int ksteps = K / 64;
  for (int kt = 0; kt < ksteps; ++kt) {
    // ---- glds staging (linear LDS dest; source col pre-swizzled) ----
    if constexpr (AMODE == 2) {
#pragma unroll
      for (int c = 0; c < 4; ++c) {
        const int row = (c * 4 + w) * 8 + glrow;  // (c*4+w)*8 is mult of 8
        const size_t go = (size_t)(m0 + row) * K + kt * 64 + glcol;
        glds16(&((const unsigned short*)Ap0)[go], &Ahi[(c * 4 + w) * 512]);
        glds16(&((const unsigned short*)Ap1)[go], &Alo[(c * 4 + w) * 512]);
      }
    }
    if constexpr (BMODE == 1) {
#pragma unroll
      for (int c = 0; c < 4; ++c) {
        const int row = (c * 4 + w) * 8 + glrow;
        const size_t go = (size_t)(n0 + row) * K + kt * 64 + glcol;
        glds16(&((const unsigned short*)Bp0)[go], &Bhi[(c * 4 + w) * 512]);
        glds16(&((const unsigned short*)Bp1)[go], &Blo[(c * 4 + w) * 512]);
      }
    }
    // ---- reg staging ----
    if constexpr (AMODE <= 1 || BMODE == 0) {
#pragma unroll
      for (int p = 0; p < 8; ++p) {
        const int row = srow + p * 16;
        const int o = swz(row, scol);
        if constexpr (AMODE == 0) {
          fvec4 av = *reinterpret_cast<const fvec4*>(
              &((const float*)Ap0)[(size_t)(m0 + row) * K + kt * 64 + scol]);
          usvec4 ah, al;
#pragma unroll
          for (int j = 0; j < 4; ++j) {
            unsigned short h, lo;
            split2(av[j], h, lo);
            ah[j] = h; al[j] = lo;
          }
          *reinterpret_cast<usvec4*>(&Ahi[o]) = ah;
          *reinterpret_cast<usvec4*>(&Alo[o]) = al;
        } else if constexpr (AMODE == 1) {
          uvec4 av = *reinterpret_cast<const uvec4*>(
              &((const unsigned int*)Ap0)[(size_t)(m0 + row) * K + kt * 64 + scol]);
          usvec4 ah, al;
#pragma unroll
          for (int j = 0; j < 4; ++j) {
            ah[j] = (unsigned short)(av[j] & 0xFFFFu);
            al[j] = (unsigned short)(av[j] >> 16);
          }
          *reinterpret_cast<usvec4*>(&Ahi[o]) = ah;
          *reinterpret_cast<usvec4*>(&Alo[o]) = al;
        }
        if constexpr (BMODE == 0) {
          fvec4 wv = *reinterpret_cast<const fvec4*>(
              &((const float*)Bp0)[(size_t)(n0 + row) * K + kt * 64 + scol]);
          usvec4 bh, bl;
#pragma unroll
          for (int j = 0; j < 4; ++j) {
            unsigned short h, lo;
            split2(wv[j], h, lo);
            bh[j] = h; bl[j] = lo;
          }
          *reinterpret_cast<usvec4*>(&Bhi[o]) = bh;
          *reinterpret_cast<usvec4*>(&Blo[o]) = bl;
        }
      }
    }
    __syncthreads();  // compiler drains vmcnt (glds) + lgkmcnt before barrier

    // ---- MFMA over the two 32-wide k sub-steps ----
#pragma unroll
    for (int ks = 0; ks < 2; ++ks) {
      bf16x8 ah[4], al[4], bh[4], bl[4];
#pragma unroll
      for (int m = 0; m < 4; ++m) {
        const int o = swz(wr * 64 + m * 16 + r16, ks * 32 + g * 8);
        ah[m] = *reinterpret_cast<const bf16x8*>(&Ahi[o]);
        al[m] = *reinterpret_cast<const bf16x8*>(&Alo[o]);
      }
#pragma unroll
      for (int n = 0; n < 4; ++n) {
        const int o = swz(wc * 64 + n * 16 + r16, ks * 32 + g * 8);
        bh[n] = *reinterpret_cast<const bf16x8*>(&Bhi[o]);
        bl[n] = *reinterpret_cast<const bf16x8*>(&Blo[o]);
      }
#pragma unroll
      for (int m = 0; m < 4; ++m)
#pragma unroll
        for (int n = 0; n < 4; ++n) {
          acc[m][n] = MFMA16(al[m], bh[n], acc[m][n]);
          acc[m][n] = MFMA16(ah[m], bl[n], acc[m][n]);
          acc[m][n] = MFMA16(ah[m], bh[n], acc[m][n]);
        }
    }
    __syncthreads();
  }

  // ---- epilogue ----
  float bv[4];
#pragma unroll
  for (int n = 0; n < 4; ++n) bv[n] = bias[n0 + wc * 64 + n * 16 + r16];

#pragma unroll
  for (int m = 0; m < 4; ++m)
#pragma unroll
    for (int n = 0; n < 4; ++n)
#pragma unroll
      for (int r = 0; r < 4; ++r) {
        const int row = m0 + wr * 64 + m * 16 + g * 4 + r;
        const int col = n0 + wc * 64 + n * 16 + r16;
        const float c = acc[m][n][r] + bv[n];
        if constexpr (OMODE == 0) {
          ((float*)Cout)[(size_t)row * N + col] = c;
        } else if constexpr (OMODE == 1) {
          ((unsigned int*)Cout)[(size_t)row * N + col] = split_pack(c);
        } else {
          ((unsigned int*)Cout)[(size_t)row * N + col] = split_pack(c * 0.125f);
        }
      }
}

// ---------------------------------------------------------------------------
// Flash attention (per (b,h)): QBLK=128 (4 waves x 2 q-groups x 16 rows),
// KBLK=64. Async-stage split: next tile's K/V global loads issued before
// current tile's compute (loads hide under ~96 MFMA + softmax), unpack/
// transpose/ds_write after the post-compute barrier. All LDS XOR-swizzled.
// OPL: 0 = packed u32 Ctx out (may alias Qpk cell-exact), 1 = hi/lo planes.
// ---------------------------------------------------------------------------
template <int OPL>
__global__ __launch_bounds__(256) void attn_fwd(
    const unsigned int* Qpk, const unsigned int* __restrict__ Kpk,
    const unsigned int* __restrict__ Vpk, unsigned int* CtxPk,
    unsigned short* CtxH, unsigned short* CtxL, int S) {
  constexpr int DM = 1024, DK = 64;
  __shared__ unsigned short Khi[64 * 64], Klo[64 * 64];
  __shared__ unsigned short Vth[64 * 64], Vtl[64 * 64];
  __shared__ unsigned short Ph[4 * 16 * 64], Pl[4 * 16 * 64];

  const int t = threadIdx.x;
  const int l = t & 63;
  const int w = t >> 6;
  const int g = l >> 4;
  const int r16 = l & 15;
  const int pw = w << 10;  // per-wave P plane base (16*64 ushorts)

  const int b = blockIdx.z, h = blockIdx.y;
  const int q0 = blockIdx.x * 128;

  // ---- Q fragments for both q-groups (packed, pre-scaled by 1/8) ----
  bf16x8 qhi[2][2], qlo[2][2];
#pragma unroll
  for (int qq = 0; qq < 2; ++qq)
#pragma unroll
    for (int ks = 0; ks < 2; ++ks) {
      const unsigned int* qrow =
          &Qpk[(size_t)(b * S + q0 + qq * 64 + w * 16 + r16) * DM + h * DK + ks * 32 + g * 8];
      uvec4 u0 = *reinterpret_cast<const uvec4*>(qrow);
      uvec4 u1 = *reinterpret_cast<const uvec4*>(qrow + 4);
#pragma unroll
      for (int j = 0; j < 4; ++j) {
        qhi[qq][ks][j] = (short)(u0[j] & 0xFFFFu);
        qlo[qq][ks][j] = (short)(u0[j] >> 16);
        qhi[qq][ks][4 + j] = (short)(u1[j] & 0xFFFFu);
        qlo[qq][ks][4 + j] = (short)(u1[j] >> 16);
      }
    }

  f32x4 o[2][4];
#pragma unroll
  for (int qq = 0; qq < 2; ++qq)
#pragma unroll
    for (int nf = 0; nf < 4; ++nf) o[qq][nf] = (f32x4){0.f, 0.f, 0.f, 0.f};
  float mrow[2][4], lrow[2][4];
#pragma unroll
  for (int qq = 0; qq < 2; ++qq)
#pragma unroll
    for (int r = 0; r < 4; ++r) { mrow[qq][r] = -1e30f; lrow[qq][r] = 0.f; }

  const int srow = t >> 4;        // staging k-row 0..15 (+16/pass)
  const int scol = (t & 15) * 4;  // element col in d
  const int s4 = l >> 4;          // V-transpose quadrant
  const bool sb1 = (s4 >> 1) & 1;
  const bool sb0 = s4 & 1;

  uvec4 kreg[4], vreg[4];  // in-flight next-tile staging registers

  auto LOADTILE = [&](int kt) {
#pragma unroll
    for (int p = 0; p < 4; ++p) {
      const size_t gb = (size_t)(b * S + kt * 64 + srow + p * 16) * DM + h * DK + scol;
      kreg[p] = *reinterpret_cast<const uvec4*>(&Kpk[gb]);
      vreg[p] = *reinterpret_cast<const uvec4*>(&Vpk[gb]);
    }
  };
  auto WRITETILE = [&]() {
#pragma unroll
    for (int p = 0; p < 4; ++p) {
      const int row = srow + p * 16;  // k index within tile
      usvec4 kh, kl;
#pragma unroll
      for (int j = 0; j < 4; ++j) {
        kh[j] = (unsigned short)(kreg[p][j] & 0xFFFFu);
        kl[j] = (unsigned short)(kreg[p][j] >> 16);
      }
      const int ko = swz(row, scol);
      *reinterpret_cast<usvec4*>(&Khi[ko]) = kh;
      *reinterpret_cast<usvec4*>(&Klo[ko]) = kl;

      // 4x4 transpose across s4 (lanes ^32 then ^16), packed u32 elements.
      unsigned int pv0 = vreg[p][0], pv1 = vreg[p][1];
      unsigned int pv2 = vreg[p][2], pv3 = vreg[p][3];
      {
        unsigned int t0 = sb1 ? pv0 : pv2;
        unsigned int t1 = sb1 ? pv1 : pv3;
        unsigned int r0 = __shfl_xor((int)t0, 32);
        unsigned int r1 = __shfl_xor((int)t1, 32);
        if (sb1) { pv0 = r0; pv1 = r1; } else { pv2 = r0; pv3 = r1; }
      }
      {
        unsigned int t0 = sb0 ? pv0 : pv1;
        unsigned int t1 = sb0 ? pv2 : pv3;
        unsigned int r0 = __shfl_xor((int)t0, 16);
        unsigned int r1 = __shfl_xor((int)t1, 16);
        if (sb0) { pv0 = r0; pv2 = r1; } else { pv1 = r0; pv3 = r1; }
      }
      const int d = 4 * r16 + s4;
      const int kb = p * 16 + w * 4;
      usvec4 vh, vl;
      vh[0] = (unsigned short)(pv0 & 0xFFFFu); vl[0] = (unsigned short)(pv0 >> 16);
      vh[1] = (unsigned short)(pv1 & 0xFFFFu); vl[1] = (unsigned short)(pv1 >> 16);
      vh[2] = (unsigned short)(pv2 & 0xFFFFu); vl[2] = (unsigned short)(pv2 >> 16);
      vh[3] = (unsigned short)(pv3 & 0xFFFFu); vl[3] = (unsigned short)(pv3 >> 16);
      const int vo = swz(d, kb);
      *reinterpret_cast<usvec4*>(&Vth[vo]) = vh;
      *reinterpret_cast<usvec4*>(&Vtl[vo]) = vl;
    }
  };

  LOADTILE(0);
  WRITETILE();
  __syncthreads();

  const int nt = S / 64;
  for (int kt = 0; kt < nt; ++kt) {
    if (kt + 1 < nt) LOADTILE(kt + 1);  // in flight across the compute phase

#pragma unroll
    for (int qq = 0; qq < 2; ++qq) {
      // ---- scores S = (Q/8) @ K^T ----
      f32x4 s[4];
#pragma unroll
      for (int nf = 0; nf < 4; ++nf) s[nf] = (f32x4){0.f, 0.f, 0.f, 0.f};
      __builtin_amdgcn_s_setprio(1);
#pragma unroll
      for (int ks = 0; ks < 2; ++ks) {
#pragma unroll
        for (int nf = 0; nf < 4; ++nf) {
          const int o2 = swz(nf * 16 + r16, ks * 32 + g * 8);
          bf16x8 kh = *reinterpret_cast<const bf16x8*>(&Khi[o2]);
          bf16x8 kl = *reinterpret_cast<const bf16x8*>(&Klo[o2]);
          s[nf] = MFMA16(qlo[qq][ks], kh, s[nf]);
          s[nf] = MFMA16(qhi[qq][ks], kl, s[nf]);
          s[nf] = MFMA16(qhi[qq][ks], kh, s[nf]);
        }
      }
      __builtin_amdgcn_s_setprio(0);

      // ---- online softmax (rows = 4*g + r; 16-lane + 4-frag reduce) ----
#pragma unroll
      for (int r = 0; r < 4; ++r) {
        float sm = fmaxf(fmaxf(s[0][r], s[1][r]), fmaxf(s[2][r], s[3][r]));
        sm = fmaxf(sm, __shfl_xor(sm, 1));
        sm = fmaxf(sm, __shfl_xor(sm, 2));
        sm = fmaxf(sm, __shfl_xor(sm, 4));
        sm = fmaxf(sm, __shfl_xor(sm, 8));
        const float mnew = fmaxf(mrow[qq][r], sm);
        const float f = __expf(mrow[qq][r] - mnew);
        mrow[qq][r] = mnew;
        float rs = 0.f;
#pragma unroll
        for (int nf = 0; nf < 4; ++nf) {
          const float p = __expf(s[nf][r] - mnew);
          s[nf][r] = p;
          rs += p;
        }
        rs += __shfl_xor(rs, 1);
        rs += __shfl_xor(rs, 2);
        rs += __shfl_xor(rs, 4);
        rs += __shfl_xor(rs, 8);
        lrow[qq][r] = lrow[qq][r] * f + rs;
#pragma unroll
        for (int nf = 0; nf < 4; ++nf) o[qq][nf][r] *= f;
      }

      // ---- write P to per-wave swizzled hi/lo planes ----
#pragma unroll
      for (int nf = 0; nf < 4; ++nf)
#pragma unroll
        for (int r = 0; r < 4; ++r) {
          unsigned short hi, lo;
          split2(s[nf][r], hi, lo);
          const int po = pw + swz(g * 4 + r, nf * 16 + r16);
          Ph[po] = hi;
          Pl[po] = lo;
        }
      // same-wave LDS write->read: DS ops are in program order per wave.

      // ---- PV: O += P @ V (direct b128 frag reads from planes) ----
      __builtin_amdgcn_s_setprio(1);
#pragma unroll
      for (int ks = 0; ks < 2; ++ks) {
        const int po = pw + swz(r16, ks * 32 + g * 8);
        bf16x8 ph = *reinterpret_cast<const bf16x8*>(&Ph[po]);
        bf16x8 pl = *reinterpret_cast<const bf16x8*>(&Pl[po]);
#pragma unroll
        for (int nf = 0; nf < 4; ++nf) {
          const int vo = swz(nf * 16 + r16, ks * 32 + g * 8);
          bf16x8 vh = *reinterpret_cast<const bf16x8*>(&Vth[vo]);
          bf16x8 vl = *reinterpret_cast<const bf16x8*>(&Vtl[vo]);
          o[qq][nf] = MFMA16(pl, vh, o[qq][nf]);
          o[qq][nf] = MFMA16(ph, vl, o[qq][nf]);
          o[qq][nf] = MFMA16(ph, vh, o[qq][nf]);
        }
      }
      __builtin_amdgcn_s_setprio(0);
    }
    __syncthreads();                    // all LDS reads of tile kt done
    if (kt + 1 < nt) WRITETILE();       // staged regs -> LDS (tile kt+1)
    __syncthreads();
  }

  // ---- epilogue: O / l ----
#pragma unroll
  for (int qq = 0; qq < 2; ++qq)
#pragma unroll
    for (int r = 0; r < 4; ++r) {
      const float inv = 1.0f / lrow[qq][r];
      const int row = q0 + qq * 64 + w * 16 + g * 4 + r;
#pragma unroll
      for (int nf = 0; nf < 4; ++nf) {
        const size_t idx = ((size_t)b * S + row) * DM + h * DK + nf * 16 + r16;
        const float val = o[qq][nf][r] * inv;
        if constexpr (OPL == 0) {
          CtxPk[idx] = split_pack(val);
        } else {
          unsigned short hi, lo;
          split2(val, hi, lo);
          CtxH[idx] = hi;
          CtxL[idx] = lo;
        }
      }
    }
}

// ---------------------------------------------------------------------------
extern "C" void kernel_launch(void* const* d_in, const int* in_sizes, int n_in,
                              void* d_out, int out_size, void* d_ws, size_t ws_size,
                              hipStream_t stream) {
  const float* q  = (const float*)d_in[0];
  const float* k  = (const float*)d_in[1];
  const float* v  = (const float*)d_in[2];
  const float* Wq = (const float*)d_in[3];
  const float* bq = (const float*)d_in[4];
  const float* Wk = (const float*)d_in[5];
  const float* bk = (const float*)d_in[6];
  const float* Wv = (const float*)d_in[7];
  const float* bv = (const float*)d_in[8];
  const float* Wo = (const float*)d_in[9];
  const float* bo = (const float*)d_in[10];

  const int DM = 1024;
  const int S = 2048;
  const int BS = in_sizes[0] / DM;  // B*S = 8192
  const int B = BS / S;
  const size_t MB = 1024 * 1024;

  const int NW = DM * DM;
  const int NI = BS * DM;
  const int cgW = NW / (256 * 4);
  const int cgI = NI / (256 * 4);
  dim3 ggrid(DM / 128, BS / 128);  // (8, 64)
  dim3 agrid(S / 128, 16, B);      // QBLK=128

  char* wsb = (char*)d_ws;

  if (ws_size >= 144 * MB) {
    // FULL: Th/Tl (input planes, later Ctx planes) | Qpk | Kpk | Vpk | W planes
    unsigned short* Th = (unsigned short*)(wsb);            // 16 MB
    unsigned short* Tl = (unsigned short*)(wsb + 16 * MB);  // 16 MB
    unsigned int* Qpk = (unsigned int*)(wsb + 32 * MB);
    unsigned int* Kpk = (unsigned int*)(wsb + 64 * MB);
    unsigned int* Vpk = (unsigned int*)(wsb + 96 * MB);
    unsigned short* Wp = (unsigned short*)(wsb + 128 * MB);
    unsigned short *Wqh = Wp + 0 * MB, *Wql = Wp + 1 * MB;
    unsigned short *Wkh = Wp + 2 * MB, *Wkl = Wp + 3 * MB;
    unsigned short *Wvh = Wp + 4 * MB, *Wvl = Wp + 5 * MB;
    unsigned short *Woh = Wp + 6 * MB, *Wol = Wp + 7 * MB;

    convert_split<<<cgW, 256, 0, stream>>>(Wq, Wqh, Wql, NW);
    convert_split<<<cgW, 256, 0, stream>>>(Wk, Wkh, Wkl, NW);
    convert_split<<<cgW, 256, 0, stream>>>(Wv, Wvh, Wvl, NW);
    convert_split<<<cgW, 256, 0, stream>>>(Wo, Woh, Wol, NW);

    convert_split<<<cgI, 256, 0, stream>>>(q, Th, Tl, NI);
    gemm_k<2, 1, 2><<<ggrid, 256, 0, stream>>>(Th, Tl, Wqh, Wql, bq, Qpk, BS, DM, DM);
    convert_split<<<cgI, 256, 0, stream>>>(k, Th, Tl, NI);
    gemm_k<2, 1, 1><<<ggrid, 256, 0, stream>>>(Th, Tl, Wkh, Wkl, bk, Kpk, BS, DM, DM);
    convert_split<<<cgI, 256, 0, stream>>>(v, Th, Tl, NI);
    gemm_k<2, 1, 1><<<ggrid, 256, 0, stream>>>(Th, Tl, Wvh, Wvl, bv, Vpk, BS, DM, DM);

    // attention writes Ctx planes into Th/Tl (free after V-GEMM; no aliasing)
    attn_fwd<1><<<agrid, 256, 0, stream>>>(Qpk, Kpk, Vpk, nullptr, Th, Tl, S);

    gemm_k<2, 1, 0><<<ggrid, 256, 0, stream>>>(Th, Tl, Woh, Wol, bo, d_out, BS, DM, DM);
  } else if (ws_size >= 112 * MB) {
    // MID: Qpk | Kpk | Vpk | W planes. A reg-staged; B via global_load_lds.
    unsigned int* Qpk = (unsigned int*)(wsb);
    unsigned int* Kpk = (unsigned int*)(wsb + 32 * MB);
    unsigned int* Vpk = (unsigned int*)(wsb + 64 * MB);
    unsigned short* Wp = (unsigned short*)(wsb + 96 * MB);
    unsigned short *Wqh = Wp + 0 * MB, *Wql = Wp + 1 * MB;
    unsigned short *Wkh = Wp + 2 * MB, *Wkl = Wp + 3 * MB;
    unsigned short *Wvh = Wp + 4 * MB, *Wvl = Wp + 5 * MB;
    unsigned short *Woh = Wp + 6 * MB, *Wol = Wp + 7 * MB;

    convert_split<<<cgW, 256, 0, stream>>>(Wq, Wqh, Wql, NW);
    convert_split<<<cgW, 256, 0, stream>>>(Wk, Wkh, Wkl, NW);
    convert_split<<<cgW, 256, 0, stream>>>(Wv, Wvh, Wvl, NW);
    convert_split<<<cgW, 256, 0, stream>>>(Wo, Woh, Wol, NW);

    gemm_k<0, 1, 2><<<ggrid, 256, 0, stream>>>(q, nullptr, Wqh, Wql, bq, Qpk, BS, DM, DM);
    gemm_k<0, 1, 1><<<ggrid, 256, 0, stream>>>(k, nullptr, Wkh, Wkl, bk, Kpk, BS, DM, DM);
    gemm_k<0, 1, 1><<<ggrid, 256, 0, stream>>>(v, nullptr, Wvh, Wvl, bv, Vpk, BS, DM, DM);

    attn_fwd<0><<<agrid, 256, 0, stream>>>(Qpk, Kpk, Vpk, Qpk, nullptr, nullptr, S);

    gemm_k<1, 1, 0><<<ggrid, 256, 0, stream>>>(Qpk, nullptr, Woh, Wol, bo, d_out, BS, DM, DM);
  } else {
    // MIN (96 MB, hardware-proven): all reg-staged, no pre-split weights.
    unsigned int* Qpk = (unsigned int*)(wsb);
    unsigned int* Kpk = (unsigned int*)(wsb + 32 * MB);
    unsigned int* Vpk = (unsigned int*)(wsb + 64 * MB);

    gemm_k<0, 0, 2><<<ggrid, 256, 0, stream>>>(q, nullptr, Wq, nullptr, bq, Qpk, BS, DM, DM);
    gemm_k<0, 0, 1><<<ggrid, 256, 0, stream>>>(k, nullptr, Wk, nullptr, bk, Kpk, BS, DM, DM);
    gemm_k<0, 0, 1><<<ggrid, 256, 0, stream>>>(v, nullptr, Wv, nullptr, bv, Vpk, BS, DM, DM);

    attn_fwd<0><<<agrid, 256, 0, stream>>>(Qpk, Kpk, Vpk, Qpk, nullptr, nullptr, S);

    gemm_k<1, 0, 0><<<ggrid, 256, 0, stream>>>(Qpk, nullptr, Wo, nullptr, bo, d_out, BS, DM, DM);
  }
}

// Round 11
// 699.575 us; speedup vs baseline: 1.5230x; 1.0955x over previous
//
#include <hip/hip_runtime.h>
#include <hip/hip_bf16.h>

// MHA forward, fp32 I/O, MI355X (gfx950).
// All matmuls via bf16 split-precision MFMA (x = hi + lo bf16;
// x*y ~= hi*hi + hi*lo + lo*hi, fp32 accum). No fp32-input MFMA on CDNA4.
//
// R11 = R8/R9/R10 resubmitted (timeout / container-fail / timeout).
// vs R7 (R7 measured: total 766us; attn 434us MfmaUtil 20.6% VALUBusy
// 44.5% Occupancy 21.8% -> shfl-chain stall-bound; GEMMs ~70us each):
//  - Attention softmax restructured via SWAPPED QK^T: compute mfma(K,Q)
//    (K-frag LDS reads identical to old B-frag reads; Q regs unchanged).
//    Output S^T has q lane-local -> row reduce = in-lane tree + 2 shfl_xor
//    (was 32 shfl per qq per tile). Rescale factor broadcast with 4 shfl.
//  - THR=0 defer-max gate: skip O/l rescale when no row max grew (f==1,
//    bit-identical skip).
//  - GEMM side unchanged from R7.

typedef __attribute__((ext_vector_type(8))) short bf16x8;
typedef __attribute__((ext_vector_type(4))) float f32x4;
typedef __attribute__((ext_vector_type(4))) float fvec4;
typedef __attribute__((ext_vector_type(4))) unsigned int uvec4;
typedef __attribute__((ext_vector_type(4))) unsigned short usvec4;

#define MFMA16(a, b, c) __builtin_amdgcn_mfma_f32_16x16x32_bf16((a), (b), (c), 0, 0, 0)

static __device__ __forceinline__ unsigned short f2bf(float f) {
  unsigned u = __builtin_bit_cast(unsigned, f);
  unsigned r = u + 0x7FFFu + ((u >> 16) & 1u);  // RNE
  return (unsigned short)(r >> 16);
}
static __device__ __forceinline__ float bf2f(unsigned short h) {
  unsigned u = ((unsigned)h) << 16;
  return __builtin_bit_cast(float, u);
}
static __device__ __forceinline__ void split2(float x, unsigned short& hi, unsigned short& lo) {
  hi = f2bf(x);
  lo = f2bf(x - bf2f(hi));
}
static __device__ __forceinline__ unsigned int split_pack(float x) {
  unsigned short hi, lo;
  split2(x, hi, lo);
  return ((unsigned)lo << 16) | (unsigned)hi;
}

// Swizzled index into a [R][64]-ushort (128B-row) LDS plane.
// 16B slot s of row r lives at physical slot (s ^ (r&7)).
static __device__ __forceinline__ int swz(int row, int col_us) {
  return (row << 6) + ((((col_us >> 3) ^ row) & 7) << 3) + (col_us & 7);
}

// Async global->LDS, 16B per lane. LDS dest must be wave-uniform base
// (HW writes lane i at base + i*16). Global src is per-lane.
static __device__ __forceinline__ void glds16(const void* g, void* l) {
  __builtin_amdgcn_global_load_lds(
      (const __attribute__((address_space(1))) void*)g,
      (__attribute__((address_space(3))) void*)l, 16, 0, 0);
}

// ---------------------------------------------------------------------------
// One-time converter: fp32 -> hi/lo bf16 planes (memory-bound).
// ---------------------------------------------------------------------------
__global__ __launch_bounds__(256) void convert_split(
    const float* __restrict__ in, unsigned short* __restrict__ hp,
    unsigned short* __restrict__ lp, int n) {
  const int i = (blockIdx.x * 256 + threadIdx.x) * 4;
  if (i >= n) return;
  fvec4 x = *reinterpret_cast<const fvec4*>(&in[i]);
  usvec4 h, l;
#pragma unroll
  for (int j = 0; j < 4; ++j) {
    unsigned short hi, lo;
    split2(x[j], hi, lo);
    h[j] = hi; l[j] = lo;
  }
  *reinterpret_cast<usvec4*>(&hp[i]) = h;
  *reinterpret_cast<usvec4*>(&lp[i]) = l;
}

// ---------------------------------------------------------------------------
// GEMM: C[M,N] = A[M,K] @ W[N,K]^T + bias[N]
// Tile 128x128, BK=64, 4 waves of 64x64 (4x4 16x16x32 frags), swizzled LDS.
// AMODE: 0 = A fp32 (split in-kernel, reg-staged)
//        1 = A packed u32 (unpack, reg-staged)
//        2 = A pre-split hi/lo planes (global_load_lds, pre-swizzled source)
// BMODE: 0 = B fp32 (reg-staged)   1 = B planes (global_load_lds)
// OMODE: 0 = fp32 out, 1 = packed u32 out, 2 = packed u32 scaled 0.125 (Q).
// ---------------------------------------------------------------------------
template <int AMODE, int BMODE, int OMODE>
__global__ __launch_bounds__(256) void gemm_k(
    const void* __restrict__ Ap0, const void* __restrict__ Ap1,
    const void* __restrict__ Bp0, const void* __restrict__ Bp1,
    const float* __restrict__ bias, void* __restrict__ Cout,
    int M, int N, int K) {
  __shared__ unsigned short Ahi[128 * 64], Alo[128 * 64];
  __shared__ unsigned short Bhi[128 * 64], Blo[128 * 64];

  const int t = threadIdx.x;
  const int l = t & 63;
  const int w = t >> 6;
  const int g = l >> 4;
  const int r16 = l & 15;
  const int wr = w >> 1, wc = w & 1;

  const int m0 = blockIdx.y * 128;
  const int n0 = blockIdx.x * 128;

  const int srow = t >> 4;         // reg-staging row 0..15 per pass
  const int scol = (t & 15) * 4;   // element col
  // glds lane coords: 8 rows x 8 slots of 16B per wave-call
  const int glrow = l >> 3;                    // row within 8-row chunk
  const int glcol = ((l & 7) ^ glrow) * 8;     // pre-swizzled source col (us)

  f32x4 acc[4][4];
#pragma unroll
  for (int m = 0; m < 4; ++m)
#pragma unroll
    for (int n = 0; n < 4; ++n) acc[m][n] = (f32x4){0.f, 0.f, 0.f, 0.f};

  const int ksteps = K / 64;
  for (int kt = 0; kt < ksteps; ++kt) {
    // ---- glds staging (linear LDS dest; source col pre-swizzled) ----
    if constexpr (AMODE == 2) {
#pragma unroll
      for (int c = 0; c < 4; ++c) {
        const int row = (c * 4 + w) * 8 + glrow;  // (c*4+w)*8 is mult of 8
        const size_t go = (size_t)(m0 + row) * K + kt * 64 + glcol;
        glds16(&((const unsigned short*)Ap0)[go], &Ahi[(c * 4 + w) * 512]);
        glds16(&((const unsigned short*)Ap1)[go], &Alo[(c * 4 + w) * 512]);
      }
    }
    if constexpr (BMODE == 1) {
#pragma unroll
      for (int c = 0; c < 4; ++c) {
        const int row = (c * 4 + w) * 8 + glrow;
        const size_t go = (size_t)(n0 + row) * K + kt * 64 + glcol;
        glds16(&((const unsigned short*)Bp0)[go], &Bhi[(c * 4 + w) * 512]);
        glds16(&((const unsigned short*)Bp1)[go], &Blo[(c * 4 + w) * 512]);
      }
    }
    // ---- reg staging ----
    if constexpr (AMODE <= 1 || BMODE == 0) {
#pragma unroll
      for (int p = 0; p < 8; ++p) {
        const int row = srow + p * 16;
        const int o = swz(row, scol);
        if constexpr (AMODE == 0) {
          fvec4 av = *reinterpret_cast<const fvec4*>(
              &((const float*)Ap0)[(size_t)(m0 + row) * K + kt * 64 + scol]);
          usvec4 ah, al;
#pragma unroll
          for (int j = 0; j < 4; ++j) {
            unsigned short h, lo;
            split2(av[j], h, lo);
            ah[j] = h; al[j] = lo;
          }
          *reinterpret_cast<usvec4*>(&Ahi[o]) = ah;
          *reinterpret_cast<usvec4*>(&Alo[o]) = al;
        } else if constexpr (AMODE == 1) {
          uvec4 av = *reinterpret_cast<const uvec4*>(
              &((const unsigned int*)Ap0)[(size_t)(m0 + row) * K + kt * 64 + scol]);
          usvec4 ah, al;
#pragma unroll
          for (int j = 0; j < 4; ++j) {
            ah[j] = (unsigned short)(av[j] & 0xFFFFu);
            al[j] = (unsigned short)(av[j] >> 16);
          }
          *reinterpret_cast<usvec4*>(&Ahi[o]) = ah;
          *reinterpret_cast<usvec4*>(&Alo[o]) = al;
        }
        if constexpr (BMODE == 0) {
          fvec4 wv = *reinterpret_cast<const fvec4*>(
              &((const float*)Bp0)[(size_t)(n0 + row) * K + kt * 64 + scol]);
          usvec4 bh, bl;
#pragma unroll
          for (int j = 0; j < 4; ++j) {
            unsigned short h, lo;
            split2(wv[j], h, lo);
            bh[j] = h; bl[j] = lo;
          }
          *reinterpret_cast<usvec4*>(&Bhi[o]) = bh;
          *reinterpret_cast<usvec4*>(&Blo[o]) = bl;
        }
      }
    }
    __syncthreads();  // compiler drains vmcnt (glds) + lgkmcnt before barrier

    // ---- MFMA over the two 32-wide k sub-steps ----
#pragma unroll
    for (int ks = 0; ks < 2; ++ks) {
      bf16x8 ah[4], al[4], bh[4], bl[4];
#pragma unroll
      for (int m = 0; m < 4; ++m) {
        const int o = swz(wr * 64 + m * 16 + r16, ks * 32 + g * 8);
        ah[m] = *reinterpret_cast<const bf16x8*>(&Ahi[o]);
        al[m] = *reinterpret_cast<const bf16x8*>(&Alo[o]);
      }
#pragma unroll
      for (int n = 0; n < 4; ++n) {
        const int o = swz(wc * 64 + n * 16 + r16, ks * 32 + g * 8);
        bh[n] = *reinterpret_cast<const bf16x8*>(&Bhi[o]);
        bl[n] = *reinterpret_cast<const bf16x8*>(&Blo[o]);
      }
#pragma unroll
      for (int m = 0; m < 4; ++m)
#pragma unroll
        for (int n = 0; n < 4; ++n) {
          acc[m][n] = MFMA16(al[m], bh[n], acc[m][n]);
          acc[m][n] = MFMA16(ah[m], bl[n], acc[m][n]);
          acc[m][n] = MFMA16(ah[m], bh[n], acc[m][n]);
        }
    }
    __syncthreads();
  }

  // ---- epilogue ----
  float bv[4];
#pragma unroll
  for (int n = 0; n < 4; ++n) bv[n] = bias[n0 + wc * 64 + n * 16 + r16];

#pragma unroll
  for (int m = 0; m < 4; ++m)
#pragma unroll
    for (int n = 0; n < 4; ++n)
#pragma unroll
      for (int r = 0; r < 4; ++r) {
        const int row = m0 + wr * 64 + m * 16 + g * 4 + r;
        const int col = n0 + wc * 64 + n * 16 + r16;
        const float c = acc[m][n][r] + bv[n];
        if constexpr (OMODE == 0) {
          ((float*)Cout)[(size_t)row * N + col] = c;
        } else if constexpr (OMODE == 1) {
          ((unsigned int*)Cout)[(size_t)row * N + col] = split_pack(c);
        } else {
          ((unsigned int*)Cout)[(size_t)row * N + col] = split_pack(c * 0.125f);
        }
      }
}

// ---------------------------------------------------------------------------
// Flash attention (per (b,h)): QBLK=128 (4 waves x 2 q-groups x 16 rows),
// KBLK=64. Swapped QK^T: s[i] = mfma(K_frag_i, Q) -> lane holds
// S^T[k = i*16 + 4g + r][q = r16]; softmax row-reduce = in-lane tree +
// shfl_xor(16) + shfl_xor(32). Rescale factor f (per q = r16) broadcast to
// O rows (q = 4g+r) with 4 shfl. THR=0 defer gate skips rescale when no
// row max grew (bit-identical skip). P written to per-wave hi/lo planes at
// [q = r16][k = i*16+4g+r]; PV reads unchanged. Async-stage split for K/V.
// OPL: 0 = packed u32 Ctx out (may alias Qpk cell-exact), 1 = hi/lo planes.
// ---------------------------------------------------------------------------
template <int OPL>
__global__ __launch_bounds__(256) void attn_fwd(
    const unsigned int* Qpk, const unsigned int* __restrict__ Kpk,
    const unsigned int* __restrict__ Vpk, unsigned int* CtxPk,
    unsigned short* CtxH, unsigned short* CtxL, int S) {
  constexpr int DM = 1024, DK = 64;
  __shared__ unsigned short Khi[64 * 64], Klo[64 * 64];
  __shared__ unsigned short Vth[64 * 64], Vtl[64 * 64];
  __shared__ unsigned short Ph[4 * 16 * 64], Pl[4 * 16 * 64];

  const int t = threadIdx.x;
  const int l = t & 63;
  const int w = t >> 6;
  const int g = l >> 4;
  const int r16 = l & 15;
  const int pw = w << 10;  // per-wave P plane base (16*64 ushorts)

  const int b = blockIdx.z, h = blockIdx.y;
  const int q0 = blockIdx.x * 128;

  // ---- Q fragments for both q-groups (packed, pre-scaled by 1/8) ----
  bf16x8 qhi[2][2], qlo[2][2];
#pragma unroll
  for (int qq = 0; qq < 2; ++qq)
#pragma unroll
    for (int ks = 0; ks < 2; ++ks) {
      const unsigned int* qrow =
          &Qpk[(size_t)(b * S + q0 + qq * 64 + w * 16 + r16) * DM + h * DK + ks * 32 + g * 8];
      uvec4 u0 = *reinterpret_cast<const uvec4*>(qrow);
      uvec4 u1 = *reinterpret_cast<const uvec4*>(qrow + 4);
#pragma unroll
      for (int j = 0; j < 4; ++j) {
        qhi[qq][ks][j] = (short)(u0[j] & 0xFFFFu);
        qlo[qq][ks][j] = (short)(u0[j] >> 16);
        qhi[qq][ks][4 + j] = (short)(u1[j] & 0xFFFFu);
        qlo[qq][ks][4 + j] = (short)(u1[j] >> 16);
      }
    }

  f32x4 o[2][4];
#pragma unroll
  for (int qq = 0; qq < 2; ++qq)
#pragma unroll
    for (int nf = 0; nf < 4; ++nf) o[qq][nf] = (f32x4){0.f, 0.f, 0.f, 0.f};
  float m_sm[2] = {-1e30f, -1e30f};  // running max for q = r16 (replicated over g)
  float l_sm[2] = {0.f, 0.f};        // running sum for q = r16

  const int srow = t >> 4;        // staging k-row 0..15 (+16/pass)
  const int scol = (t & 15) * 4;  // element col in d
  const int s4 = l >> 4;          // V-transpose quadrant
  const bool sb1 = (s4 >> 1) & 1;
  const bool sb0 = s4 & 1;

  uvec4 kreg[4], vreg[4];  // in-flight next-tile staging registers

  auto LOADTILE = [&](int kt) {
#pragma unroll
    for (int p = 0; p < 4; ++p) {
      const size_t gb = (size_t)(b * S + kt * 64 + srow + p * 16) * DM + h * DK + scol;
      kreg[p] = *reinterpret_cast<const uvec4*>(&Kpk[gb]);
      vreg[p] = *reinterpret_cast<const uvec4*>(&Vpk[gb]);
    }
  };
  auto WRITETILE = [&]() {
#pragma unroll
    for (int p = 0; p < 4; ++p) {
      const int row = srow + p * 16;  // k index within tile
      usvec4 kh, kl;
#pragma unroll
      for (int j = 0; j < 4; ++j) {
        kh[j] = (unsigned short)(kreg[p][j] & 0xFFFFu);
        kl[j] = (unsigned short)(kreg[p][j] >> 16);
      }
      const int ko = swz(row, scol);
      *reinterpret_cast<usvec4*>(&Khi[ko]) = kh;
      *reinterpret_cast<usvec4*>(&Klo[ko]) = kl;

      // 4x4 transpose across s4 (lanes ^32 then ^16), packed u32 elements.
      unsigned int pv0 = vreg[p][0], pv1 = vreg[p][1];
      unsigned int pv2 = vreg[p][2], pv3 = vreg[p][3];
      {
        unsigned int t0 = sb1 ? pv0 : pv2;
        unsigned int t1 = sb1 ? pv1 : pv3;
        unsigned int r0 = __shfl_xor((int)t0, 32);
        unsigned int r1 = __shfl_xor((int)t1, 32);
        if (sb1) { pv0 = r0; pv1 = r1; } else { pv2 = r0; pv3 = r1; }
      }
      {
        unsigned int t0 = sb0 ? pv0 : pv1;
        unsigned int t1 = sb0 ? pv2 : pv3;
        unsigned int r0 = __shfl_xor((int)t0, 16);
        unsigned int r1 = __shfl_xor((int)t1, 16);
        if (sb0) { pv0 = r0; pv2 = r1; } else { pv1 = r0; pv3 = r1; }
      }
      const int d = 4 * r16 + s4;
      const int kb = p * 16 + w * 4;
      usvec4 vh, vl;
      vh[0] = (unsigned short)(pv0 & 0xFFFFu); vl[0] = (unsigned short)(pv0 >> 16);
      vh[1] = (unsigned short)(pv1 & 0xFFFFu); vl[1] = (unsigned short)(pv1 >> 16);
      vh[2] = (unsigned short)(pv2 & 0xFFFFu); vl[2] = (unsigned short)(pv2 >> 16);
      vh[3] = (unsigned short)(pv3 & 0xFFFFu); vl[3] = (unsigned short)(pv3 >> 16);
      const int vo = swz(d, kb);
      *reinterpret_cast<usvec4*>(&Vth[vo]) = vh;
      *reinterpret_cast<usvec4*>(&Vtl[vo]) = vl;
    }
  };

  LOADTILE(0);
  WRITETILE();
  __syncthreads();

  const int nt = S / 64;
  for (int kt = 0; kt < nt; ++kt) {
    if (kt + 1 < nt) LOADTILE(kt + 1);  // in flight across the compute phase

#pragma unroll
    for (int qq = 0; qq < 2; ++qq) {
      // ---- scores S^T = K @ Q^T (swapped operands; same split terms) ----
      f32x4 s[4];
#pragma unroll
      for (int i = 0; i < 4; ++i) s[i] = (f32x4){0.f, 0.f, 0.f, 0.f};
      __builtin_amdgcn_s_setprio(1);
#pragma unroll
      for (int ks = 0; ks < 2; ++ks) {
#pragma unroll
        for (int i = 0; i < 4; ++i) {
          const int o2 = swz(i * 16 + r16, ks * 32 + g * 8);
          bf16x8 kh = *reinterpret_cast<const bf16x8*>(&Khi[o2]);
          bf16x8 kl = *reinterpret_cast<const bf16x8*>(&Klo[o2]);
          s[i] = MFMA16(kh, qlo[qq][ks], s[i]);
          s[i] = MFMA16(kl, qhi[qq][ks], s[i]);
          s[i] = MFMA16(kh, qhi[qq][ks], s[i]);
        }
      }
      __builtin_amdgcn_s_setprio(0);
      // lane now holds S^T[k = i*16 + 4g + r][q = r16] in s[i][r]

      // ---- online softmax for q = r16 (in-lane tree + 2 shfl) ----
      f32x4 x0, x1;
#pragma unroll
      for (int r = 0; r < 4; ++r) x0[r] = fmaxf(s[0][r], s[1][r]);
#pragma unroll
      for (int r = 0; r < 4; ++r) x1[r] = fmaxf(s[2][r], s[3][r]);
      float pm = fmaxf(fmaxf(fmaxf(x0[0], x0[1]), fmaxf(x0[2], x0[3])),
                       fmaxf(fmaxf(x1[0], x1[1]), fmaxf(x1[2], x1[3])));
      pm = fmaxf(pm, __shfl_xor(pm, 16));
      pm = fmaxf(pm, __shfl_xor(pm, 32));

      if (!__all(pm <= m_sm[qq])) {  // THR=0 defer gate: skip == identity
        const float mnew = fmaxf(m_sm[qq], pm);
        const float f = __expf(m_sm[qq] - mnew);
        m_sm[qq] = mnew;
        l_sm[qq] *= f;
#pragma unroll
        for (int r = 0; r < 4; ++r) {
          const float fr = __shfl(f, (l & 48) | (4 * g + r));  // f for q=4g+r
#pragma unroll
          for (int nf = 0; nf < 4; ++nf) o[qq][nf][r] *= fr;
        }
      }

      float rs = 0.f;
#pragma unroll
      for (int i = 0; i < 4; ++i)
#pragma unroll
        for (int r = 0; r < 4; ++r) {
          const float p = __expf(s[i][r] - m_sm[qq]);
          s[i][r] = p;
          rs += p;
        }
      rs += __shfl_xor(rs, 16);
      rs += __shfl_xor(rs, 32);
      l_sm[qq] += rs;

      // ---- write P to per-wave swizzled hi/lo planes: [q=r16][k=i*16+4g+r] ----
#pragma unroll
      for (int i = 0; i < 4; ++i)
#pragma unroll
        for (int r = 0; r < 4; ++r) {
          unsigned short hi, lo;
          split2(s[i][r], hi, lo);
          const int po = pw + swz(r16, i * 16 + 4 * g + r);
          Ph[po] = hi;
          Pl[po] = lo;
        }
      // same-wave LDS write->read: DS ops are in program order per wave.

      // ---- PV: O += P @ V (direct b128 frag reads from planes) ----
      __builtin_amdgcn_s_setprio(1);
#pragma unroll
      for (int ks = 0; ks < 2; ++ks) {
        const int po = pw + swz(r16, ks * 32 + g * 8);
        bf16x8 ph = *reinterpret_cast<const bf16x8*>(&Ph[po]);
        bf16x8 pl = *reinterpret_cast<const bf16x8*>(&Pl[po]);
#pragma unroll
        for (int nf = 0; nf < 4; ++nf) {
          const int vo = swz(nf * 16 + r16, ks * 32 + g * 8);
          bf16x8 vh = *reinterpret_cast<const bf16x8*>(&Vth[vo]);
          bf16x8 vl = *reinterpret_cast<const bf16x8*>(&Vtl[vo]);
          o[qq][nf] = MFMA16(pl, vh, o[qq][nf]);
          o[qq][nf] = MFMA16(ph, vl, o[qq][nf]);
          o[qq][nf] = MFMA16(ph, vh, o[qq][nf]);
        }
      }
      __builtin_amdgcn_s_setprio(0);
    }
    __syncthreads();                    // all LDS reads of tile kt done
    if (kt + 1 < nt) WRITETILE();       // staged regs -> LDS (tile kt+1)
    __syncthreads();
  }

  // ---- epilogue: O / l ----
#pragma unroll
  for (int qq = 0; qq < 2; ++qq) {
    const float inv = 1.0f / l_sm[qq];  // for q = r16
#pragma unroll
    for (int r = 0; r < 4; ++r) {
      const float ir = __shfl(inv, (l & 48) | (4 * g + r));  // for q = 4g+r
      const int row = q0 + qq * 64 + w * 16 + g * 4 + r;
#pragma unroll
      for (int nf = 0; nf < 4; ++nf) {
        const size_t idx = ((size_t)b * S + row) * DM + h * DK + nf * 16 + r16;
        const float val = o[qq][nf][r] * ir;
        if constexpr (OPL == 0) {
          CtxPk[idx] = split_pack(val);
        } else {
          unsigned short hi, lo;
          split2(val, hi, lo);
          CtxH[idx] = hi;
          CtxL[idx] = lo;
        }
      }
    }
  }
}

// ---------------------------------------------------------------------------
extern "C" void kernel_launch(void* const* d_in, const int* in_sizes, int n_in,
                              void* d_out, int out_size, void* d_ws, size_t ws_size,
                              hipStream_t stream) {
  const float* q  = (const float*)d_in[0];
  const float* k  = (const float*)d_in[1];
  const float* v  = (const float*)d_in[2];
  const float* Wq = (const float*)d_in[3];
  const float* bq = (const float*)d_in[4];
  const float* Wk = (const float*)d_in[5];
  const float* bk = (const float*)d_in[6];
  const float* Wv = (const float*)d_in[7];
  const float* bv = (const float*)d_in[8];
  const float* Wo = (const float*)d_in[9];
  const float* bo = (const float*)d_in[10];

  const int DM = 1024;
  const int S = 2048;
  const int BS = in_sizes[0] / DM;  // B*S = 8192
  const int B = BS / S;
  const size_t MB = 1024 * 1024;

  const int NW = DM * DM;
  const int NI = BS * DM;
  const int cgW = NW / (256 * 4);
  const int cgI = NI / (256 * 4);
  dim3 ggrid(DM / 128, BS / 128);  // (8, 64)
  dim3 agrid(S / 128, 16, B);      // QBLK=128

  char* wsb = (char*)d_ws;

  if (ws_size >= 144 * MB) {
    // FULL: Th/Tl (input planes, later Ctx planes) | Qpk | Kpk | Vpk | W planes
    unsigned short* Th = (unsigned short*)(wsb);            // 16 MB
    unsigned short* Tl = (unsigned short*)(wsb + 16 * MB);  // 16 MB
    unsigned int* Qpk = (unsigned int*)(wsb + 32 * MB);
    unsigned int* Kpk = (unsigned int*)(wsb + 64 * MB);
    unsigned int* Vpk = (unsigned int*)(wsb + 96 * MB);
    unsigned short* Wp = (unsigned short*)(wsb + 128 * MB);
    unsigned short *Wqh = Wp + 0 * MB, *Wql = Wp + 1 * MB;
    unsigned short *Wkh = Wp + 2 * MB, *Wkl = Wp + 3 * MB;
    unsigned short *Wvh = Wp + 4 * MB, *Wvl = Wp + 5 * MB;
    unsigned short *Woh = Wp + 6 * MB, *Wol = Wp + 7 * MB;

    convert_split<<<cgW, 256, 0, stream>>>(Wq, Wqh, Wql, NW);
    convert_split<<<cgW, 256, 0, stream>>>(Wk, Wkh, Wkl, NW);
    convert_split<<<cgW, 256, 0, stream>>>(Wv, Wvh, Wvl, NW);
    convert_split<<<cgW, 256, 0, stream>>>(Wo, Woh, Wol, NW);

    convert_split<<<cgI, 256, 0, stream>>>(q, Th, Tl, NI);
    gemm_k<2, 1, 2><<<ggrid, 256, 0, stream>>>(Th, Tl, Wqh, Wql, bq, Qpk, BS, DM, DM);
    convert_split<<<cgI, 256, 0, stream>>>(k, Th, Tl, NI);
    gemm_k<2, 1, 1><<<ggrid, 256, 0, stream>>>(Th, Tl, Wkh, Wkl, bk, Kpk, BS, DM, DM);
    convert_split<<<cgI, 256, 0, stream>>>(v, Th, Tl, NI);
    gemm_k<2, 1, 1><<<ggrid, 256, 0, stream>>>(Th, Tl, Wvh, Wvl, bv, Vpk, BS, DM, DM);

    // attention writes Ctx planes into Th/Tl (free after V-GEMM; no aliasing)
    attn_fwd<1><<<agrid, 256, 0, stream>>>(Qpk, Kpk, Vpk, nullptr, Th, Tl, S);

    gemm_k<2, 1, 0><<<ggrid, 256, 0, stream>>>(Th, Tl, Woh, Wol, bo, d_out, BS, DM, DM);
  } else if (ws_size >= 112 * MB) {
    // MID: Qpk | Kpk | Vpk | W planes. A reg-staged; B via global_load_lds.
    unsigned int* Qpk = (unsigned int*)(wsb);
    unsigned int* Kpk = (unsigned int*)(wsb + 32 * MB);
    unsigned int* Vpk = (unsigned int*)(wsb + 64 * MB);
    unsigned short* Wp = (unsigned short*)(wsb + 96 * MB);
    unsigned short *Wqh = Wp + 0 * MB, *Wql = Wp + 1 * MB;
    unsigned short *Wkh = Wp + 2 * MB, *Wkl = Wp + 3 * MB;
    unsigned short *Wvh = Wp + 4 * MB, *Wvl = Wp + 5 * MB;
    unsigned short *Woh = Wp + 6 * MB, *Wol = Wp + 7 * MB;

    convert_split<<<cgW, 256, 0, stream>>>(Wq, Wqh, Wql, NW);
    convert_split<<<cgW, 256, 0, stream>>>(Wk, Wkh, Wkl, NW);
    convert_split<<<cgW, 256, 0, stream>>>(Wv, Wvh, Wvl, NW);
    convert_split<<<cgW, 256, 0, stream>>>(Wo, Woh, Wol, NW);

    gemm_k<0, 1, 2><<<ggrid, 256, 0, stream>>>(q, nullptr, Wqh, Wql, bq, Qpk, BS, DM, DM);
    gemm_k<0, 1, 1><<<ggrid, 256, 0, stream>>>(k, nullptr, Wkh, Wkl, bk, Kpk, BS, DM, DM);
    gemm_k<0, 1, 1><<<ggrid, 256, 0, stream>>>(v, nullptr, Wvh, Wvl, bv, Vpk, BS, DM, DM);

    attn_fwd<0><<<agrid, 256, 0, stream>>>(Qpk, Kpk, Vpk, Qpk, nullptr, nullptr, S);

    gemm_k<1, 1, 0><<<ggrid, 256, 0, stream>>>(Qpk, nullptr, Woh, Wol, bo, d_out, BS, DM, DM);
  } else {
    // MIN (96 MB, hardware-proven): all reg-staged, no pre-split weights.
    unsigned int* Qpk = (unsigned int*)(wsb);
    unsigned int* Kpk = (unsigned int*)(wsb + 32 * MB);
    unsigned int* Vpk = (unsigned int*)(wsb + 64 * MB);

    gemm_k<0, 0, 2><<<ggrid, 256, 0, stream>>>(q, nullptr, Wq, nullptr, bq, Qpk, BS, DM, DM);
    gemm_k<0, 0, 1><<<ggrid, 256, 0, stream>>>(k, nullptr, Wk, nullptr, bk, Kpk, BS, DM, DM);
    gemm_k<0, 0, 1><<<ggrid, 256, 0, stream>>>(v, nullptr, Wv, nullptr, bv, Vpk, BS, DM, DM);

    attn_fwd<0><<<agrid, 256, 0, stream>>>(Qpk, Kpk, Vpk, Qpk, nullptr, nullptr, S);

    gemm_k<1, 0, 0><<<ggrid, 256, 0, stream>>>(Qpk, nullptr, Wo, nullptr, bo, d_out, BS, DM, DM);
  }
}